// Round 9
// baseline (204.797 us; speedup 1.0000x reference)
//
#include <hip/hip_runtime.h>

using u16 = unsigned short;
using u32 = unsigned int;
using short8 = __attribute__((ext_vector_type(8))) short;
using short4v = __attribute__((ext_vector_type(4))) short;
using bf16x8 = __attribute__((ext_vector_type(8))) __bf16;
using f32x4 = __attribute__((ext_vector_type(4))) float;

#define ALPHA_INV (1.0f / (128.0f * 100.0f))

__device__ __forceinline__ u32 swz(u32 off, u32 row) { return off ^ ((row & 7u) << 4); }

__device__ __forceinline__ u16 f2bf(float x) {
  u32 u = __float_as_uint(x);
  u32 r = u + 0x7fffu + ((u >> 16) & 1u);
  return (u16)(r >> 16);
}

__device__ __forceinline__ float bf2f(u16 x) {
  u32 u = ((u32)x) << 16;
  return __uint_as_float(u);
}

__device__ __forceinline__ f32x4 mfma(bf16x8 a, bf16x8 b, f32x4 c) {
  return __builtin_amdgcn_mfma_f32_16x16x32_bf16(a, b, c, 0, 0, 0);
}

// async 16B global->LDS; LDS dest is wave-uniform base + lane*16
__device__ __forceinline__ void gl16(const void* g, void* l) {
  __builtin_amdgcn_global_load_lds(
      (const __attribute__((address_space(1))) unsigned int*)g,
      (__attribute__((address_space(3))) unsigned int*)l, 16, 0, 0);
}

// ---------------------------------------------------------------------------
// Weight transpose + bf16 + PRE-SWIZZLE: w[tap][cin][256] fp32 ->
// wt[tap][256 n][cin] bf16 with each 64-u16 k-slice swizzled by n&7.
// ---------------------------------------------------------------------------
__global__ void wtrans(const float* __restrict__ w, u16* __restrict__ o, int rows, int cin) {
  int idx = blockIdx.x * 256 + threadIdx.x;
  if (idx >= rows * 256) return;
  int row = idx >> 8, n = idx & 255;
  int tap = row / cin, c = row - tap * cin;
  int kc = c >> 6, ci = c & 63;
  u32 sb = (u32)(ci * 2) ^ ((u32)(n & 7) << 4);
  o[((size_t)tap * 256 + n) * cin + kc * 64 + (sb >> 1)] = f2bf(w[idx]);
}

// batch fp32 -> bf16 S, PRE-SWIZZLED per 64-u16 slice keyed by row&7
__global__ void cvt_bf16_kernel(const float* __restrict__ in, u16* __restrict__ out) {
  int i = blockIdx.x * 256 + threadIdx.x;
  float4 v = ((const float4*)in)[i];
  short4v o;
  o[0] = (short)f2bf(v.x); o[1] = (short)f2bf(v.y);
  o[2] = (short)f2bf(v.z); o[3] = (short)f2bf(v.w);
  int e = i * 4;
  int row = e >> 7, c = e & 127;
  int slice = c >> 6, ci = c & 63;
  u32 sb = (u32)(ci * 2) ^ ((u32)(row & 7) << 4);
  *(short4v*)(out + (size_t)row * 128 + slice * 64 + (sb >> 1)) = o;
}

// ---------------------------------------------------------------------------
// S (pre-swizzled) [B*T][128] bf16 -> ST [B][128][2048] bf16 (normal layout).
// ---------------------------------------------------------------------------
__global__ __launch_bounds__(256) void transpose_s(const u16* __restrict__ S,
                                                   u16* __restrict__ ST) {
  __shared__ u16 L[64 * 129];
  const int tid = threadIdx.x;
  const int t0 = blockIdx.x * 64;
  const int b = blockIdx.y;
  const u16* src = S + ((size_t)b * 2048 + t0) * 128;
#pragma unroll
  for (int it = 0; it < 4; ++it) {
    int s = tid + it * 256;
    int t = s >> 4, c8 = s & 15;
    int slice = c8 >> 3;
    u32 sb = (u32)((c8 & 7) * 16) ^ ((u32)(t & 7) << 4);  // t0%8==0
    short8 v = *(const short8*)(src + t * 128 + slice * 64 + (sb >> 1));
#pragma unroll
    for (int j = 0; j < 8; ++j) L[t * 129 + c8 * 8 + j] = (u16)v[j];
  }
  __syncthreads();
  u16* dst = ST + (size_t)b * 128 * 2048 + t0;
#pragma unroll
  for (int it = 0; it < 4; ++it) {
    int s = tid + it * 256;
    int oct = s & 7, d = s >> 3;
    short8 v;
#pragma unroll
    for (int j = 0; j < 8; ++j) v[j] = (short)L[(oct * 8 + j) * 129 + d];
    *(short8*)(dst + (size_t)d * 2048 + oct * 8) = v;
  }
}

// ---------------------------------------------------------------------------
// Causal dilated conv as GEMM. Input and weights are PRE-SWIZZLED; staging is
// global_load_lds (linear LDS dest, per-lane global src). RELU outputs are
// written pre-swizzled for the next conv; SOFTMAX output (H) is normal.
// ---------------------------------------------------------------------------
template <int CIN, int DIL, int TAPS, bool RELU, bool SOFTMAX>
__global__ __launch_bounds__(512) void conv_kernel(
    const u16* __restrict__ in, const u16* __restrict__ wt,
    const float* __restrict__ bias, u16* __restrict__ out) {
  constexpr int BM = 128, BN = 256, BK = 64;
  __shared__ alignas(16) u16 Al[BM * BK];
  __shared__ alignas(16) u16 Bl[BN * BK];
  __shared__ float redA[4][BM];
  __shared__ float redB[4][BM];

  const int tid = threadIdx.x;
  const int wid = tid >> 6, lane = tid & 63;
  const int wr = wid >> 2, wc = wid & 3;
  const int lg = lane >> 4, lq = lane & 15;
  const int row0 = blockIdx.x * BM;
  const int tloc0 = row0 & 2047;

  f32x4 acc[4][4];
#pragma unroll
  for (int i = 0; i < 4; ++i)
#pragma unroll
    for (int j = 0; j < 4; ++j) acc[i][j] = (f32x4)0.0f;

#pragma unroll
  for (int tap = 0; tap < TAPS; ++tap) {
    const int shift = (TAPS - 1 - tap) * DIL;
#pragma unroll
    for (int kc = 0; kc < CIN / BK; ++kc) {
      // stage A [128 r][64 u16] : linear LDS copy of pre-swizzled rows
      if (shift > 0 && tloc0 == 0) {
        // boundary block: masked register path, same LDS image
#pragma unroll
        for (int it = 0; it < 2; ++it) {
          int gi = tid + it * 512;
          int r = gi >> 3, cg = gi & 7;
          short8 v = (short8)0;
          if (r >= shift)
            v = *(const short8*)(in + (size_t)(row0 + r - shift) * CIN + kc * BK + cg * 8);
          *(short8*)((char*)Al + gi * 16) = v;
        }
      } else {
#pragma unroll
        for (int it = 0; it < 2; ++it) {
          int gi = tid + it * 512;
          int r = gi >> 3, cg = gi & 7;
          gl16(in + (size_t)(row0 + r - shift) * CIN + kc * BK + cg * 8,
               (char*)Al + it * 8192 + wid * 1024);
        }
      }
      // stage B [256 n][64 u16] : linear LDS copy of pre-swizzled weights
      {
        const u16* wtb = wt + ((size_t)(tap * 256)) * CIN + kc * BK;
#pragma unroll
        for (int it = 0; it < 4; ++it) {
          int gi = tid + it * 512;
          int n = gi >> 3, cg = gi & 7;
          gl16(wtb + (size_t)n * CIN + cg * 8, (char*)Bl + it * 8192 + wid * 1024);
        }
      }
      __syncthreads();
#pragma unroll
      for (int ks = 0; ks < 2; ++ks) {
        bf16x8 af[4], bfr[4];
#pragma unroll
        for (int mi = 0; mi < 4; ++mi) {
          int r = wr * 64 + mi * 16 + lq;
          af[mi] = *(const bf16x8*)((const char*)Al +
                                    swz(r * 128 + ks * 64 + lg * 16, (u32)(r - shift + 8)));
        }
#pragma unroll
        for (int ni = 0; ni < 4; ++ni) {
          int n = wc * 64 + ni * 16 + lq;
          bfr[ni] = *(const bf16x8*)((const char*)Bl + swz(n * 128 + ks * 64 + lg * 16, n));
        }
#pragma unroll
        for (int mi = 0; mi < 4; ++mi)
#pragma unroll
          for (int ni = 0; ni < 4; ++ni)
            acc[mi][ni] = mfma(af[mi], bfr[ni], acc[mi][ni]);
      }
      __syncthreads();
    }
  }

  float bcol[4];
#pragma unroll
  for (int ni = 0; ni < 4; ++ni) bcol[ni] = bias[wc * 64 + ni * 16 + lq];
#pragma unroll
  for (int mi = 0; mi < 4; ++mi)
#pragma unroll
    for (int ni = 0; ni < 4; ++ni)
#pragma unroll
      for (int rr = 0; rr < 4; ++rr) acc[mi][ni][rr] += bcol[ni];

  if constexpr (!SOFTMAX) {
    // write PRE-SWIZZLED for the next conv's global_load_lds staging
#pragma unroll
    for (int mi = 0; mi < 4; ++mi)
#pragma unroll
      for (int ni = 0; ni < 4; ++ni)
#pragma unroll
        for (int rr = 0; rr < 4; ++rr) {
          float v = acc[mi][ni][rr];
          if (RELU) v = fmaxf(v, 0.0f);
          int row = row0 + wr * 64 + mi * 16 + lg * 4 + rr;
          int col = wc * 64 + ni * 16 + lq;
          int ci = col & 63;
          u32 sb = (u32)(ci * 2) ^ ((u32)(row & 7) << 4);
          out[(size_t)row * BN + wc * 64 + (sb >> 1)] = f2bf(v);
        }
  } else {
    float tmx[4][4];
#pragma unroll
    for (int mi = 0; mi < 4; ++mi)
#pragma unroll
      for (int rr = 0; rr < 4; ++rr) {
        float v = fmaxf(fmaxf(acc[mi][0][rr], acc[mi][1][rr]),
                        fmaxf(acc[mi][2][rr], acc[mi][3][rr]));
#pragma unroll
        for (int off = 1; off < 16; off <<= 1) v = fmaxf(v, __shfl_xor(v, off));
        if (lq == 0) redA[wc][wr * 64 + mi * 16 + lg * 4 + rr] = v;
      }
    __syncthreads();
#pragma unroll
    for (int mi = 0; mi < 4; ++mi)
#pragma unroll
      for (int rr = 0; rr < 4; ++rr) {
        int rb = wr * 64 + mi * 16 + lg * 4 + rr;
        tmx[mi][rr] = fmaxf(fmaxf(redA[0][rb], redA[1][rb]),
                            fmaxf(redA[2][rb], redA[3][rb]));
      }
#pragma unroll
    for (int mi = 0; mi < 4; ++mi)
#pragma unroll
      for (int rr = 0; rr < 4; ++rr) {
        float s = 0.0f;
#pragma unroll
        for (int ni = 0; ni < 4; ++ni) {
          float p = __expf(acc[mi][ni][rr] - tmx[mi][rr]);
          acc[mi][ni][rr] = p;
          s += p;
        }
#pragma unroll
        for (int off = 1; off < 16; off <<= 1) s += __shfl_xor(s, off);
        if (lq == 0) redB[wc][wr * 64 + mi * 16 + lg * 4 + rr] = s;
      }
    __syncthreads();
#pragma unroll
    for (int mi = 0; mi < 4; ++mi)
#pragma unroll
      for (int rr = 0; rr < 4; ++rr) {
        int rb = wr * 64 + mi * 16 + lg * 4 + rr;
        float inv = 1.0f / (redB[0][rb] + redB[1][rb] + redB[2][rb] + redB[3][rb]);
        int row = row0 + rb;
#pragma unroll
        for (int ni = 0; ni < 4; ++ni) {
          int col = wc * 64 + ni * 16 + lq;
          out[(size_t)row * BN + col] = f2bf(acc[mi][ni][rr] * inv);
        }
      }
  }
}

// ---------------------------------------------------------------------------
// gchunk (unchanged): G[b][j][d][128 ml] = ST_j[d][t] @ H_j[t][ml]
// ---------------------------------------------------------------------------
__global__ __launch_bounds__(512) void gchunk(
    const u16* __restrict__ H, const u16* __restrict__ ST,
    u16* __restrict__ G0, u16* __restrict__ G1) {
  constexpr int M = 256, T = 2048;
  __shared__ alignas(16) u16 Hl[128 * 128];
  __shared__ alignas(16) u16 Sl[128 * 128];
  const int tid = threadIdx.x;
  const int wid = tid >> 6, lane = tid & 63;
  const int dg = wid >> 2, mg = wid & 3;
  const int lg = lane >> 4, lq = lane & 15;
  const int b = blockIdx.x, mh = blockIdx.y, j = blockIdx.z;
  u16* G = (mh == 0 ? G0 : G1);

#pragma unroll
  for (int it = 0; it < 4; ++it) {
    int s = tid + it * 512;
    int t = s >> 4, c8 = s & 15;
    *(short8*)((char*)Hl + swz(t * 256 + c8 * 16, t)) =
        *(const short8*)(H + ((size_t)b * T + j * 128 + t) * M + mh * 128 + c8 * 8);
  }
#pragma unroll
  for (int it = 0; it < 4; ++it) {
    int s = tid + it * 512;
    int d = s >> 4, c8 = s & 15;
    *(short8*)((char*)Sl + swz(d * 256 + c8 * 16, d)) =
        *(const short8*)(ST + ((size_t)b * 128 + d) * T + j * 128 + c8 * 8);
  }
  __syncthreads();

  f32x4 acc[4][2];
#pragma unroll
  for (int di = 0; di < 4; ++di)
#pragma unroll
    for (int mi = 0; mi < 2; ++mi) acc[di][mi] = (f32x4)0.0f;

#pragma unroll
  for (int ks = 0; ks < 4; ++ks) {
    bf16x8 sfrag[4];
#pragma unroll
    for (int di = 0; di < 4; ++di) {
      int d = dg * 64 + di * 16 + lq;
      sfrag[di] = *(const bf16x8*)((const char*)Sl + swz(d * 256 + ks * 64 + lg * 16, d));
    }
#pragma unroll
    for (int mi = 0; mi < 2; ++mi) {
      int ml = mg * 32 + mi * 16 + lq;
      short8 hr;
#pragma unroll
      for (int jj = 0; jj < 8; ++jj) {
        int t = ks * 32 + lg * 8 + jj;
        hr[jj] = (short)*(const u16*)((const char*)Hl + swz(t * 256 + ml * 2, t));
      }
      bf16x8 hfrag = __builtin_bit_cast(bf16x8, hr);
#pragma unroll
      for (int di = 0; di < 4; ++di) acc[di][mi] = mfma(sfrag[di], hfrag, acc[di][mi]);
    }
  }

  u16* Gj = G + (((size_t)b * 16 + j) << 14);
#pragma unroll
  for (int di = 0; di < 4; ++di)
#pragma unroll
    for (int mi = 0; mi < 2; ++mi)
#pragma unroll
      for (int rr = 0; rr < 4; ++rr) {
        int d = dg * 64 + di * 16 + lg * 4 + rr;
        int ml = mg * 32 + mi * 16 + lq;
        Gj[d * 128 + ml] = f2bf(acc[di][mi][rr]);
      }
}

// ---------------------------------------------------------------------------
// prefix_scan (unchanged)
// ---------------------------------------------------------------------------
__global__ __launch_bounds__(256) void prefix_scan(
    u16* __restrict__ G0, u16* __restrict__ G1, float* __restrict__ Wtmp) {
  u16* G = blockIdx.y ? G1 : G0;
  float* W = Wtmp + (size_t)blockIdx.y * (32 * 128 * 128);
  int idx = blockIdx.x * 256 + threadIdx.x;
  int mo = idx & 15, d = (idx >> 4) & 127, b = idx >> 11;
  size_t base = (((size_t)b * 16) * 128 + d) * 128 + mo * 8;
  float acc[8];
#pragma unroll
  for (int k = 0; k < 8; ++k) acc[k] = ALPHA_INV;
  for (int j = 0; j < 16; ++j) {
    u16* p = G + base + (size_t)j * 16384;
    short8 g = *(short8*)p;
    short8 c;
#pragma unroll
    for (int k = 0; k < 8; ++k) c[k] = (short)f2bf(acc[k]);
    *(short8*)p = c;
#pragma unroll
    for (int k = 0; k < 8; ++k) acc[k] += bf2f((u16)g[k]);
  }
  float* w = W + ((size_t)b * 128 + d) * 128 + mo * 8;
  *(float4*)w = make_float4(acc[0], acc[1], acc[2], acc[3]);
  *(float4*)(w + 4) = make_float4(acc[4], acc[5], acc[6], acc[7]);
}

// ---------------------------------------------------------------------------
// wfin_t (unchanged)
// ---------------------------------------------------------------------------
__global__ __launch_bounds__(256) void wfin_t(const float* __restrict__ Wtmp,
                                              float* __restrict__ wfin) {
  __shared__ float L[128 * 129];
  const int tid = threadIdx.x;
  const int b = blockIdx.x, h = blockIdx.y;
  const float* src = Wtmp + (size_t)h * (32 * 128 * 128) + (size_t)b * 16384;
#pragma unroll
  for (int it = 0; it < 16; ++it) {
    int idx = tid + it * 256;
    int d = idx >> 5, q = idx & 31;
    *(float4*)&L[d * 129 + q * 4] = *(const float4*)&src[d * 128 + q * 4];
  }
  __syncthreads();
  float* dst = wfin + (size_t)b * 32768 + (size_t)h * 16384;
#pragma unroll
  for (int it = 0; it < 16; ++it) {
    int idx = tid + it * 256;
    int ml = idx >> 5, dq = idx & 31;
    float4 v;
    v.x = L[(dq * 4 + 0) * 129 + ml];
    v.y = L[(dq * 4 + 1) * 129 + ml];
    v.z = L[(dq * 4 + 2) * 129 + ml];
    v.w = L[(dq * 4 + 3) * 129 + ml];
    *(float4*)&dst[ml * 128 + dq * 4] = v;
  }
}

// ---------------------------------------------------------------------------
// attn_chunk (unchanged)
// ---------------------------------------------------------------------------
__global__ __launch_bounds__(512) void attn_chunk(
    const u16* __restrict__ H, const u16* __restrict__ ST,
    const u16* __restrict__ C0, const u16* __restrict__ C1,
    float* __restrict__ out) {
  constexpr int M = 256, D = 128, T = 2048;
  __shared__ alignas(16) u16 Hi[128 * 256];
  __shared__ alignas(16) u16 Sl[128 * 128];
  __shared__ alignas(16) u16 Ct[128 * 128];

  const int tid = threadIdx.x;
  const int wid = tid >> 6, lane = tid & 63;
  const int lg = lane >> 4, lq = lane & 15;
  const int b = blockIdx.x, i = blockIdx.y;
  const size_t hrow0 = (size_t)b * T + i * 128;

  bf16x8 aq[8];
  {
    const u16* qrow = H + (hrow0 + wid * 16 + lq) * M;
#pragma unroll
    for (int ks = 0; ks < 8; ++ks) aq[ks] = *(const bf16x8*)(qrow + ks * 32 + lg * 8);
  }

#pragma unroll
  for (int it = 0; it < 8; ++it) {
    int s = tid + it * 512;
    int r = s >> 5, c = s & 31;
    *(short8*)((char*)Hi + swz(r * 512 + c * 16, r)) =
        *(const short8*)(H + (hrow0 + r) * M + c * 8);
  }
#pragma unroll
  for (int it = 0; it < 4; ++it) {
    int s = tid + it * 512;
    int d = s >> 4, c8 = s & 15;
    *(short8*)((char*)Sl + swz(d * 256 + c8 * 16, d)) =
        *(const short8*)(ST + ((size_t)b * D + d) * T + i * 128 + c8 * 8);
  }
  const size_t coff = ((size_t)b * 16 + i) * (128 * 128);
#pragma unroll
  for (int it = 0; it < 4; ++it) {
    int s = tid + it * 512;
    int d = s >> 4, c8 = s & 15;
    *(short8*)((char*)Ct + swz(d * 256 + c8 * 16, d)) = *(const short8*)(C0 + coff + d * 128 + c8 * 8);
  }
  __syncthreads();

  f32x4 accO[8];
#pragma unroll
  for (int df = 0; df < 8; ++df) accO[df] = (f32x4)0.0f;

#pragma unroll
  for (int ks = 0; ks < 4; ++ks)
#pragma unroll
    for (int df = 0; df < 8; ++df) {
      int d = df * 16 + lq;
      bf16x8 bf = *(const bf16x8*)((const char*)Ct + swz(d * 256 + ks * 64 + lg * 16, d));
      accO[df] = mfma(aq[ks], bf, accO[df]);
    }
  __syncthreads();
#pragma unroll
  for (int it = 0; it < 4; ++it) {
    int s = tid + it * 512;
    int d = s >> 4, c8 = s & 15;
    *(short8*)((char*)Ct + swz(d * 256 + c8 * 16, d)) = *(const short8*)(C1 + coff + d * 128 + c8 * 8);
  }
  __syncthreads();
#pragma unroll
  for (int ks = 0; ks < 4; ++ks)
#pragma unroll
    for (int df = 0; df < 8; ++df) {
      int d = df * 16 + lq;
      bf16x8 bf = *(const bf16x8*)((const char*)Ct + swz(d * 256 + ks * 64 + lg * 16, d));
      accO[df] = mfma(aq[4 + ks], bf, accO[df]);
    }
  __syncthreads();

  f32x4 accP[8];
#pragma unroll
  for (int cf = 0; cf < 8; ++cf) accP[cf] = (f32x4)0.0f;
#pragma unroll
  for (int ks = 0; ks < 8; ++ks)
#pragma unroll
    for (int cf = 0; cf < 8; ++cf) {
      int tt = cf * 16 + lq;
      bf16x8 bf = *(const bf16x8*)((const char*)Hi + swz(tt * 512 + ks * 64 + lg * 16, tt));
      accP[cf] = mfma(aq[ks], bf, accP[cf]);
    }
  char* Pw = (char*)Ct + wid * 4096;
#pragma unroll
  for (int cf = 0; cf < 8; ++cf)
#pragma unroll
    for (int rr = 0; rr < 4; ++rr) {
      int ql = lg * 4 + rr;
      int tl = cf * 16 + lq;
      float v = accP[cf][rr];
      if (tl >= wid * 16 + ql) v = 0.0f;
      *(u16*)(Pw + swz(ql * 256 + tl * 2, ql)) = f2bf(v);
    }
#pragma unroll
  for (int ks = 0; ks < 4; ++ks) {
    bf16x8 a = *(const bf16x8*)(Pw + swz(lq * 256 + ks * 64 + lg * 16, lq));
#pragma unroll
    for (int df = 0; df < 8; ++df) {
      int d = df * 16 + lq;
      bf16x8 bf = *(const bf16x8*)((const char*)Sl + swz(d * 256 + ks * 64 + lg * 16, d));
      accO[df] = mfma(a, bf, accO[df]);
    }
  }

#pragma unroll
  for (int rr = 0; rr < 4; ++rr) {
    float ssum = 0.0f;
#pragma unroll
    for (int df = 0; df < 8; ++df) ssum += accO[df][rr];
#pragma unroll
    for (int off = 1; off < 16; off <<= 1) ssum += __shfl_xor(ssum, off);
    float inv = 1.0f / ssum;
    size_t row = hrow0 + wid * 16 + lg * 4 + rr;
#pragma unroll
    for (int df = 0; df < 8; ++df)
      out[row * D + df * 16 + lq] = accO[df][rr] * inv;
  }
}

// ---------------------------------------------------------------------------
extern "C" void kernel_launch(void* const* d_in, const int* in_sizes, int n_in,
                              void* d_out, int out_size, void* d_ws, size_t ws_size,
                              hipStream_t stream) {
  const float* batch = (const float*)d_in[0];
  const float* w0 = (const float*)d_in[1];
  const float* b0 = (const float*)d_in[2];
  const float* w1 = (const float*)d_in[3];
  const float* b1 = (const float*)d_in[4];
  const float* w2 = (const float*)d_in[5];
  const float* b2 = (const float*)d_in[6];
  const float* wo = (const float*)d_in[7];
  const float* bo = (const float*)d_in[8];

  const size_t SZ_S = 16777216;     // 16MB
  const size_t SZ_BUF = 33554432;   // 32MB
  const size_t NEED = SZ_S + 2 * SZ_BUF + 786432;
  if (ws_size < NEED) return;

  char* ws = (char*)d_ws;
  // Layout (live-range safe):
  //  [0,16M):   S (dead after transpose_s)  -> G0/C0
  //  [16M,32M): bufA lower -> ST (written after conv4; bufA dead)
  //  [32M,48M): bufA upper -> G1/C1
  //  [48M,80M): bufB = H (live to end)
  //  [80M,..):  weights
  u16* S = (u16*)ws;
  u16* bufA = (u16*)(ws + SZ_S);
  u16* bufB = (u16*)(ws + SZ_S + SZ_BUF);
  u16* Wt0 = (u16*)(ws + SZ_S + 2 * SZ_BUF);
  u16* Wt1 = Wt0 + 2 * 256 * 128;
  u16* Wt2 = Wt1 + 2 * 256 * 256;
  u16* Wt3 = Wt2 + 2 * 256 * 256;
  u16* ST = bufA;
  u16* G0 = (u16*)ws;
  u16* G1 = (u16*)(ws + 2 * SZ_S);
  float* probs = (float*)d_out;
  float* wfin = probs + (size_t)32 * 2048 * 128;
  float* Wtmp = probs;

  wtrans<<<256, 256, 0, stream>>>(w0, Wt0, 2 * 128, 128);
  wtrans<<<512, 256, 0, stream>>>(w1, Wt1, 2 * 256, 256);
  wtrans<<<512, 256, 0, stream>>>(w2, Wt2, 2 * 256, 256);
  wtrans<<<256, 256, 0, stream>>>(wo, Wt3, 1 * 256, 256);
  cvt_bf16_kernel<<<8192, 256, 0, stream>>>(batch, S);

  conv_kernel<128, 1, 2, true, false><<<512, 512, 0, stream>>>(S, Wt0, b0, bufA);
  conv_kernel<256, 2, 2, true, false><<<512, 512, 0, stream>>>(bufA, Wt1, b1, bufB);
  conv_kernel<256, 4, 2, true, false><<<512, 512, 0, stream>>>(bufB, Wt2, b2, bufA);
  conv_kernel<256, 1, 1, false, true><<<512, 512, 0, stream>>>(bufA, Wt3, bo, bufB);

  transpose_s<<<dim3(32, 32), 256, 0, stream>>>(S, ST);
  gchunk<<<dim3(32, 2, 16), 512, 0, stream>>>(bufB, ST, G0, G1);
  prefix_scan<<<dim3(256, 2), 256, 0, stream>>>(G0, G1, Wtmp);
  wfin_t<<<dim3(32, 2), 256, 0, stream>>>(Wtmp, wfin);
  attn_chunk<<<dim3(32, 16), 512, 0, stream>>>(bufB, ST, G0, G1, probs);
}

// Round 10
// 200.083 us; speedup vs baseline: 1.0236x; 1.0236x over previous
//
#include <hip/hip_runtime.h>

using u16 = unsigned short;
using u32 = unsigned int;
using short8 = __attribute__((ext_vector_type(8))) short;
using short4v = __attribute__((ext_vector_type(4))) short;
using bf16x8 = __attribute__((ext_vector_type(8))) __bf16;
using f32x4 = __attribute__((ext_vector_type(4))) float;

#define ALPHA_INV (1.0f / (128.0f * 100.0f))

__device__ __forceinline__ u32 swz(u32 off, u32 row) { return off ^ ((row & 7u) << 4); }

__device__ __forceinline__ u16 f2bf(float x) {
  u32 u = __float_as_uint(x);
  u32 r = u + 0x7fffu + ((u >> 16) & 1u);
  return (u16)(r >> 16);
}

__device__ __forceinline__ float bf2f(u16 x) {
  u32 u = ((u32)x) << 16;
  return __uint_as_float(u);
}

__device__ __forceinline__ f32x4 mfma(bf16x8 a, bf16x8 b, f32x4 c) {
  return __builtin_amdgcn_mfma_f32_16x16x32_bf16(a, b, c, 0, 0, 0);
}

// async 16B global->LDS; LDS dest is wave-uniform base + lane*16
__device__ __forceinline__ void gl16(const void* g, void* l) {
  __builtin_amdgcn_global_load_lds(
      (const __attribute__((address_space(1))) unsigned int*)g,
      (__attribute__((address_space(3))) unsigned int*)l, 16, 0, 0);
}

// ---------------------------------------------------------------------------
// All 4 weight tensors: transpose + bf16 + PRE-SWIZZLE in ONE launch.
// w[tap][cin][256] fp32 -> wt[tap][256 n][cin] bf16, 64-u16 k-slices swizzled.
// ---------------------------------------------------------------------------
__global__ void wtrans_all(const float* __restrict__ w0, const float* __restrict__ w1,
                           const float* __restrict__ w2, const float* __restrict__ wo,
                           u16* __restrict__ o0, u16* __restrict__ o1,
                           u16* __restrict__ o2, u16* __restrict__ o3) {
  int blk = blockIdx.x;
  const float* w; u16* o; int cin;
  if (blk < 256)       { w = w0; o = o0; cin = 128; }
  else if (blk < 768)  { w = w1; o = o1; cin = 256; blk -= 256; }
  else if (blk < 1280) { w = w2; o = o2; cin = 256; blk -= 768; }
  else                 { w = wo; o = o3; cin = 256; blk -= 1280; }
  int idx = blk * 256 + threadIdx.x;
  int row = idx >> 8, n = idx & 255;
  int tap = row / cin, c = row - tap * cin;
  int kc = c >> 6, ci = c & 63;
  u32 sb = (u32)(ci * 2) ^ ((u32)(n & 7) << 4);
  o[((size_t)tap * 256 + n) * cin + kc * 64 + (sb >> 1)] = f2bf(w[idx]);
}

// batch fp32 -> bf16 S, PRE-SWIZZLED per 64-u16 slice keyed by row&7
__global__ void cvt_bf16_kernel(const float* __restrict__ in, u16* __restrict__ out) {
  int i = blockIdx.x * 256 + threadIdx.x;
  float4 v = ((const float4*)in)[i];
  short4v o;
  o[0] = (short)f2bf(v.x); o[1] = (short)f2bf(v.y);
  o[2] = (short)f2bf(v.z); o[3] = (short)f2bf(v.w);
  int e = i * 4;
  int row = e >> 7, c = e & 127;
  int slice = c >> 6, ci = c & 63;
  u32 sb = (u32)(ci * 2) ^ ((u32)(row & 7) << 4);
  *(short4v*)(out + (size_t)row * 128 + slice * 64 + (sb >> 1)) = o;
}

// ---------------------------------------------------------------------------
// S (pre-swizzled) [B*T][128] bf16 -> ST [B][128][2048] bf16 (normal layout).
// ---------------------------------------------------------------------------
__global__ __launch_bounds__(256) void transpose_s(const u16* __restrict__ S,
                                                   u16* __restrict__ ST) {
  __shared__ u16 L[64 * 129];
  const int tid = threadIdx.x;
  const int t0 = blockIdx.x * 64;
  const int b = blockIdx.y;
  const u16* src = S + ((size_t)b * 2048 + t0) * 128;
#pragma unroll
  for (int it = 0; it < 4; ++it) {
    int s = tid + it * 256;
    int t = s >> 4, c8 = s & 15;
    int slice = c8 >> 3;
    u32 sb = (u32)((c8 & 7) * 16) ^ ((u32)(t & 7) << 4);
    short8 v = *(const short8*)(src + t * 128 + slice * 64 + (sb >> 1));
#pragma unroll
    for (int j = 0; j < 8; ++j) L[t * 129 + c8 * 8 + j] = (u16)v[j];
  }
  __syncthreads();
  u16* dst = ST + (size_t)b * 128 * 2048 + t0;
#pragma unroll
  for (int it = 0; it < 4; ++it) {
    int s = tid + it * 256;
    int oct = s & 7, d = s >> 3;
    short8 v;
#pragma unroll
    for (int j = 0; j < 8; ++j) v[j] = (short)L[(oct * 8 + j) * 129 + d];
    *(short8*)(dst + (size_t)d * 2048 + oct * 8) = v;
  }
}

// ---------------------------------------------------------------------------
// Causal dilated conv as GEMM (unchanged from R9, proven)
// ---------------------------------------------------------------------------
template <int CIN, int DIL, int TAPS, bool RELU, bool SOFTMAX>
__global__ __launch_bounds__(512) void conv_kernel(
    const u16* __restrict__ in, const u16* __restrict__ wt,
    const float* __restrict__ bias, u16* __restrict__ out) {
  constexpr int BM = 128, BN = 256, BK = 64;
  __shared__ alignas(16) u16 Al[BM * BK];
  __shared__ alignas(16) u16 Bl[BN * BK];
  __shared__ float redA[4][BM];
  __shared__ float redB[4][BM];

  const int tid = threadIdx.x;
  const int wid = tid >> 6, lane = tid & 63;
  const int wr = wid >> 2, wc = wid & 3;
  const int lg = lane >> 4, lq = lane & 15;
  const int row0 = blockIdx.x * BM;
  const int tloc0 = row0 & 2047;

  f32x4 acc[4][4];
#pragma unroll
  for (int i = 0; i < 4; ++i)
#pragma unroll
    for (int j = 0; j < 4; ++j) acc[i][j] = (f32x4)0.0f;

#pragma unroll
  for (int tap = 0; tap < TAPS; ++tap) {
    const int shift = (TAPS - 1 - tap) * DIL;
#pragma unroll
    for (int kc = 0; kc < CIN / BK; ++kc) {
      if (shift > 0 && tloc0 == 0) {
#pragma unroll
        for (int it = 0; it < 2; ++it) {
          int gi = tid + it * 512;
          int r = gi >> 3, cg = gi & 7;
          short8 v = (short8)0;
          if (r >= shift)
            v = *(const short8*)(in + (size_t)(row0 + r - shift) * CIN + kc * BK + cg * 8);
          *(short8*)((char*)Al + gi * 16) = v;
        }
      } else {
#pragma unroll
        for (int it = 0; it < 2; ++it) {
          int gi = tid + it * 512;
          int r = gi >> 3, cg = gi & 7;
          gl16(in + (size_t)(row0 + r - shift) * CIN + kc * BK + cg * 8,
               (char*)Al + it * 8192 + wid * 1024);
        }
      }
      {
        const u16* wtb = wt + ((size_t)(tap * 256)) * CIN + kc * BK;
#pragma unroll
        for (int it = 0; it < 4; ++it) {
          int gi = tid + it * 512;
          int n = gi >> 3, cg = gi & 7;
          gl16(wtb + (size_t)n * CIN + cg * 8, (char*)Bl + it * 8192 + wid * 1024);
        }
      }
      __syncthreads();
#pragma unroll
      for (int ks = 0; ks < 2; ++ks) {
        bf16x8 af[4], bfr[4];
#pragma unroll
        for (int mi = 0; mi < 4; ++mi) {
          int r = wr * 64 + mi * 16 + lq;
          af[mi] = *(const bf16x8*)((const char*)Al +
                                    swz(r * 128 + ks * 64 + lg * 16, (u32)(r - shift + 8)));
        }
#pragma unroll
        for (int ni = 0; ni < 4; ++ni) {
          int n = wc * 64 + ni * 16 + lq;
          bfr[ni] = *(const bf16x8*)((const char*)Bl + swz(n * 128 + ks * 64 + lg * 16, n));
        }
#pragma unroll
        for (int mi = 0; mi < 4; ++mi)
#pragma unroll
          for (int ni = 0; ni < 4; ++ni)
            acc[mi][ni] = mfma(af[mi], bfr[ni], acc[mi][ni]);
      }
      __syncthreads();
    }
  }

  float bcol[4];
#pragma unroll
  for (int ni = 0; ni < 4; ++ni) bcol[ni] = bias[wc * 64 + ni * 16 + lq];
#pragma unroll
  for (int mi = 0; mi < 4; ++mi)
#pragma unroll
    for (int ni = 0; ni < 4; ++ni)
#pragma unroll
      for (int rr = 0; rr < 4; ++rr) acc[mi][ni][rr] += bcol[ni];

  if constexpr (!SOFTMAX) {
#pragma unroll
    for (int mi = 0; mi < 4; ++mi)
#pragma unroll
      for (int ni = 0; ni < 4; ++ni)
#pragma unroll
        for (int rr = 0; rr < 4; ++rr) {
          float v = acc[mi][ni][rr];
          if (RELU) v = fmaxf(v, 0.0f);
          int row = row0 + wr * 64 + mi * 16 + lg * 4 + rr;
          int col = wc * 64 + ni * 16 + lq;
          int ci = col & 63;
          u32 sb = (u32)(ci * 2) ^ ((u32)(row & 7) << 4);
          out[(size_t)row * BN + wc * 64 + (sb >> 1)] = f2bf(v);
        }
  } else {
    float tmx[4][4];
#pragma unroll
    for (int mi = 0; mi < 4; ++mi)
#pragma unroll
      for (int rr = 0; rr < 4; ++rr) {
        float v = fmaxf(fmaxf(acc[mi][0][rr], acc[mi][1][rr]),
                        fmaxf(acc[mi][2][rr], acc[mi][3][rr]));
#pragma unroll
        for (int off = 1; off < 16; off <<= 1) v = fmaxf(v, __shfl_xor(v, off));
        if (lq == 0) redA[wc][wr * 64 + mi * 16 + lg * 4 + rr] = v;
      }
    __syncthreads();
#pragma unroll
    for (int mi = 0; mi < 4; ++mi)
#pragma unroll
      for (int rr = 0; rr < 4; ++rr) {
        int rb = wr * 64 + mi * 16 + lg * 4 + rr;
        tmx[mi][rr] = fmaxf(fmaxf(redA[0][rb], redA[1][rb]),
                            fmaxf(redA[2][rb], redA[3][rb]));
      }
#pragma unroll
    for (int mi = 0; mi < 4; ++mi)
#pragma unroll
      for (int rr = 0; rr < 4; ++rr) {
        float s = 0.0f;
#pragma unroll
        for (int ni = 0; ni < 4; ++ni) {
          float p = __expf(acc[mi][ni][rr] - tmx[mi][rr]);
          acc[mi][ni][rr] = p;
          s += p;
        }
#pragma unroll
        for (int off = 1; off < 16; off <<= 1) s += __shfl_xor(s, off);
        if (lq == 0) redB[wc][wr * 64 + mi * 16 + lg * 4 + rr] = s;
      }
    __syncthreads();
#pragma unroll
    for (int mi = 0; mi < 4; ++mi)
#pragma unroll
      for (int rr = 0; rr < 4; ++rr) {
        int rb = wr * 64 + mi * 16 + lg * 4 + rr;
        float inv = 1.0f / (redB[0][rb] + redB[1][rb] + redB[2][rb] + redB[3][rb]);
        int row = row0 + rb;
#pragma unroll
        for (int ni = 0; ni < 4; ++ni) {
          int col = wc * 64 + ni * 16 + lq;
          out[(size_t)row * BN + col] = f2bf(acc[mi][ni][rr] * inv);
        }
      }
  }
}

// ---------------------------------------------------------------------------
// gchunk: G[b][j][d][128 ml] = ST_j[d][t] @ H_j[t][ml].
// H staged TRANSPOSED (Hl[ml][t], scatter spread ~2-way by swizzle) so the
// B-fragment build is a vector ds_read_b128 instead of 8 scalar gathers.
// ---------------------------------------------------------------------------
__global__ __launch_bounds__(512) void gchunk(
    const u16* __restrict__ H, const u16* __restrict__ ST,
    u16* __restrict__ G0, u16* __restrict__ G1) {
  constexpr int M = 256, T = 2048;
  __shared__ alignas(16) u16 Hl[128 * 128];  // [ml][t] rows 256B swz
  __shared__ alignas(16) u16 Sl[128 * 128];  // [d][t]  rows 256B swz
  const int tid = threadIdx.x;
  const int wid = tid >> 6, lane = tid & 63;
  const int dg = wid >> 2, mg = wid & 3;
  const int lg = lane >> 4, lq = lane & 15;
  const int b = blockIdx.x, mh = blockIdx.y, j = blockIdx.z;
  u16* G = (mh == 0 ? G0 : G1);

#pragma unroll
  for (int it = 0; it < 4; ++it) {
    int s = tid + it * 512;
    int t = s >> 4, c8 = s & 15;
    short8 v = *(const short8*)(H + ((size_t)b * T + j * 128 + t) * M + mh * 128 + c8 * 8);
#pragma unroll
    for (int jj = 0; jj < 8; ++jj) {
      int ml = c8 * 8 + jj;
      *(u16*)((char*)Hl + swz(ml * 256 + t * 2, ml)) = (u16)v[jj];
    }
  }
#pragma unroll
  for (int it = 0; it < 4; ++it) {
    int s = tid + it * 512;
    int d = s >> 4, c8 = s & 15;
    *(short8*)((char*)Sl + swz(d * 256 + c8 * 16, d)) =
        *(const short8*)(ST + ((size_t)b * 128 + d) * T + j * 128 + c8 * 8);
  }
  __syncthreads();

  f32x4 acc[4][2];
#pragma unroll
  for (int di = 0; di < 4; ++di)
#pragma unroll
    for (int mi = 0; mi < 2; ++mi) acc[di][mi] = (f32x4)0.0f;

#pragma unroll
  for (int ks = 0; ks < 4; ++ks) {
    bf16x8 sfrag[4];
#pragma unroll
    for (int di = 0; di < 4; ++di) {
      int d = dg * 64 + di * 16 + lq;
      sfrag[di] = *(const bf16x8*)((const char*)Sl + swz(d * 256 + ks * 64 + lg * 16, d));
    }
#pragma unroll
    for (int mi = 0; mi < 2; ++mi) {
      int ml = mg * 32 + mi * 16 + lq;
      bf16x8 hfrag =
          *(const bf16x8*)((const char*)Hl + swz(ml * 256 + ks * 64 + lg * 16, ml));
#pragma unroll
      for (int di = 0; di < 4; ++di) acc[di][mi] = mfma(sfrag[di], hfrag, acc[di][mi]);
    }
  }

  u16* Gj = G + (((size_t)b * 16 + j) << 14);
#pragma unroll
  for (int di = 0; di < 4; ++di)
#pragma unroll
    for (int mi = 0; mi < 2; ++mi)
#pragma unroll
      for (int rr = 0; rr < 4; ++rr) {
        int d = dg * 64 + di * 16 + lg * 4 + rr;
        int ml = mg * 32 + mi * 16 + lq;
        Gj[d * 128 + ml] = f2bf(acc[di][mi][rr]);
      }
}

// ---------------------------------------------------------------------------
// prefix_wfin: exclusive scan over j (in-place G -> C) + DIRECT transposed
// W_final write (merges old prefix_scan + wfin_t, no Wtmp round-trip).
// grid (32 b, 2 mh, 8 dseg), 256 thr: thread = (d within seg, m-octet).
// ---------------------------------------------------------------------------
__global__ __launch_bounds__(256) void prefix_wfin(
    u16* __restrict__ G0, u16* __restrict__ G1, float* __restrict__ wfin) {
  __shared__ float Wl[16][132];
  const int b = blockIdx.x, mh = blockIdx.y, ds = blockIdx.z;
  u16* G = mh ? G1 : G0;
  const int tid = threadIdx.x;
  const int mo = tid & 15, dg = tid >> 4;  // dg 0..15
  const int d = ds * 16 + dg;
  size_t base = (((size_t)b * 16) << 14) + d * 128 + mo * 8;
  float acc[8];
#pragma unroll
  for (int k = 0; k < 8; ++k) acc[k] = ALPHA_INV;
  for (int j = 0; j < 16; ++j) {
    u16* p = G + base + ((size_t)j << 14);
    short8 g = *(short8*)p;
    short8 c;
#pragma unroll
    for (int k = 0; k < 8; ++k) c[k] = (short)f2bf(acc[k]);
    *(short8*)p = c;
#pragma unroll
    for (int k = 0; k < 8; ++k) acc[k] += bf2f((u16)g[k]);
  }
#pragma unroll
  for (int k = 0; k < 8; ++k) Wl[dg][mo * 8 + k] = acc[k];
  __syncthreads();
  const int ml = tid >> 1, dq = tid & 1;
  const int dl0 = dq * 8;
  float* dst = wfin + ((size_t)b * 256 + mh * 128 + ml) * 128 + ds * 16 + dl0;
  float4 v0 = make_float4(Wl[dl0][ml], Wl[dl0 + 1][ml], Wl[dl0 + 2][ml], Wl[dl0 + 3][ml]);
  float4 v1 = make_float4(Wl[dl0 + 4][ml], Wl[dl0 + 5][ml], Wl[dl0 + 6][ml], Wl[dl0 + 7][ml]);
  *(float4*)dst = v0;
  *(float4*)(dst + 4) = v1;
}

// ---------------------------------------------------------------------------
// attn_chunk: accO = H_i @ C_i + strict_tri(H_i H_i^T) @ S_i.
// T14-lite: C1 half preloaded to regs before first barrier; post-num0 restage
// is a pure ds_write (no global latency between barriers).
// ---------------------------------------------------------------------------
__global__ __launch_bounds__(512) void attn_chunk(
    const u16* __restrict__ H, const u16* __restrict__ ST,
    const u16* __restrict__ C0, const u16* __restrict__ C1,
    float* __restrict__ out) {
  constexpr int M = 256, D = 128, T = 2048;
  __shared__ alignas(16) u16 Hi[128 * 256];
  __shared__ alignas(16) u16 Sl[128 * 128];
  __shared__ alignas(16) u16 Ct[128 * 128];

  const int tid = threadIdx.x;
  const int wid = tid >> 6, lane = tid & 63;
  const int lg = lane >> 4, lq = lane & 15;
  const int b = blockIdx.x, i = blockIdx.y;
  const size_t hrow0 = (size_t)b * T + i * 128;
  const size_t coff = ((size_t)b * 16 + i) * (128 * 128);

  bf16x8 aq[8];
  {
    const u16* qrow = H + (hrow0 + wid * 16 + lq) * M;
#pragma unroll
    for (int ks = 0; ks < 8; ++ks) aq[ks] = *(const bf16x8*)(qrow + ks * 32 + lg * 8);
  }

  // preload C1 half-tile into registers (consumed after num0)
  short8 ct1r[4];
#pragma unroll
  for (int it = 0; it < 4; ++it) {
    int s = tid + it * 512;
    int d = s >> 4, c8 = s & 15;
    ct1r[it] = *(const short8*)(C1 + coff + d * 128 + c8 * 8);
  }

#pragma unroll
  for (int it = 0; it < 8; ++it) {
    int s = tid + it * 512;
    int r = s >> 5, c = s & 31;
    *(short8*)((char*)Hi + swz(r * 512 + c * 16, r)) =
        *(const short8*)(H + (hrow0 + r) * M + c * 8);
  }
#pragma unroll
  for (int it = 0; it < 4; ++it) {
    int s = tid + it * 512;
    int d = s >> 4, c8 = s & 15;
    *(short8*)((char*)Sl + swz(d * 256 + c8 * 16, d)) =
        *(const short8*)(ST + ((size_t)b * D + d) * T + i * 128 + c8 * 8);
  }
#pragma unroll
  for (int it = 0; it < 4; ++it) {
    int s = tid + it * 512;
    int d = s >> 4, c8 = s & 15;
    *(short8*)((char*)Ct + swz(d * 256 + c8 * 16, d)) = *(const short8*)(C0 + coff + d * 128 + c8 * 8);
  }
  __syncthreads();

  f32x4 accO[8];
#pragma unroll
  for (int df = 0; df < 8; ++df) accO[df] = (f32x4)0.0f;

#pragma unroll
  for (int ks = 0; ks < 4; ++ks)
#pragma unroll
    for (int df = 0; df < 8; ++df) {
      int d = df * 16 + lq;
      bf16x8 bf = *(const bf16x8*)((const char*)Ct + swz(d * 256 + ks * 64 + lg * 16, d));
      accO[df] = mfma(aq[ks], bf, accO[df]);
    }
  __syncthreads();
#pragma unroll
  for (int it = 0; it < 4; ++it) {
    int s = tid + it * 512;
    int d = s >> 4, c8 = s & 15;
    *(short8*)((char*)Ct + swz(d * 256 + c8 * 16, d)) = ct1r[it];
  }
  __syncthreads();
#pragma unroll
  for (int ks = 0; ks < 4; ++ks)
#pragma unroll
    for (int df = 0; df < 8; ++df) {
      int d = df * 16 + lq;
      bf16x8 bf = *(const bf16x8*)((const char*)Ct + swz(d * 256 + ks * 64 + lg * 16, d));
      accO[df] = mfma(aq[4 + ks], bf, accO[df]);
    }
  __syncthreads();

  f32x4 accP[8];
#pragma unroll
  for (int cf = 0; cf < 8; ++cf) accP[cf] = (f32x4)0.0f;
#pragma unroll
  for (int ks = 0; ks < 8; ++ks)
#pragma unroll
    for (int cf = 0; cf < 8; ++cf) {
      int tt = cf * 16 + lq;
      bf16x8 bf = *(const bf16x8*)((const char*)Hi + swz(tt * 512 + ks * 64 + lg * 16, tt));
      accP[cf] = mfma(aq[ks], bf, accP[cf]);
    }
  char* Pw = (char*)Ct + wid * 4096;
#pragma unroll
  for (int cf = 0; cf < 8; ++cf)
#pragma unroll
    for (int rr = 0; rr < 4; ++rr) {
      int ql = lg * 4 + rr;
      int tl = cf * 16 + lq;
      float v = accP[cf][rr];
      if (tl >= wid * 16 + ql) v = 0.0f;
      *(u16*)(Pw + swz(ql * 256 + tl * 2, ql)) = f2bf(v);
    }
#pragma unroll
  for (int ks = 0; ks < 4; ++ks) {
    bf16x8 a = *(const bf16x8*)(Pw + swz(lq * 256 + ks * 64 + lg * 16, lq));
#pragma unroll
    for (int df = 0; df < 8; ++df) {
      int d = df * 16 + lq;
      bf16x8 bf = *(const bf16x8*)((const char*)Sl + swz(d * 256 + ks * 64 + lg * 16, d));
      accO[df] = mfma(a, bf, accO[df]);
    }
  }

#pragma unroll
  for (int rr = 0; rr < 4; ++rr) {
    float ssum = 0.0f;
#pragma unroll
    for (int df = 0; df < 8; ++df) ssum += accO[df][rr];
#pragma unroll
    for (int off = 1; off < 16; off <<= 1) ssum += __shfl_xor(ssum, off);
    float inv = 1.0f / ssum;
    size_t row = hrow0 + wid * 16 + lg * 4 + rr;
#pragma unroll
    for (int df = 0; df < 8; ++df)
      out[row * D + df * 16 + lq] = accO[df][rr] * inv;
  }
}

// ---------------------------------------------------------------------------
extern "C" void kernel_launch(void* const* d_in, const int* in_sizes, int n_in,
                              void* d_out, int out_size, void* d_ws, size_t ws_size,
                              hipStream_t stream) {
  const float* batch = (const float*)d_in[0];
  const float* w0 = (const float*)d_in[1];
  const float* b0 = (const float*)d_in[2];
  const float* w1 = (const float*)d_in[3];
  const float* b1 = (const float*)d_in[4];
  const float* w2 = (const float*)d_in[5];
  const float* b2 = (const float*)d_in[6];
  const float* wo = (const float*)d_in[7];
  const float* bo = (const float*)d_in[8];

  const size_t SZ_S = 16777216;     // 16MB
  const size_t SZ_BUF = 33554432;   // 32MB
  const size_t NEED = SZ_S + 2 * SZ_BUF + 786432;
  if (ws_size < NEED) return;

  char* ws = (char*)d_ws;
  // Layout (live-range safe):
  //  [0,16M):   S (dead after transpose_s)  -> G0/C0
  //  [16M,32M): bufA lower -> ST (written after conv4; bufA dead)
  //  [32M,48M): bufA upper -> G1/C1
  //  [48M,80M): bufB = H (live to end)
  //  [80M,..):  weights
  u16* S = (u16*)ws;
  u16* bufA = (u16*)(ws + SZ_S);
  u16* bufB = (u16*)(ws + SZ_S + SZ_BUF);
  u16* Wt0 = (u16*)(ws + SZ_S + 2 * SZ_BUF);
  u16* Wt1 = Wt0 + 2 * 256 * 128;
  u16* Wt2 = Wt1 + 2 * 256 * 256;
  u16* Wt3 = Wt2 + 2 * 256 * 256;
  u16* ST = bufA;
  u16* G0 = (u16*)ws;
  u16* G1 = (u16*)(ws + 2 * SZ_S);
  float* probs = (float*)d_out;
  float* wfin = probs + (size_t)32 * 2048 * 128;

  wtrans_all<<<1536, 256, 0, stream>>>(w0, w1, w2, wo, Wt0, Wt1, Wt2, Wt3);
  cvt_bf16_kernel<<<8192, 256, 0, stream>>>(batch, S);

  conv_kernel<128, 1, 2, true, false><<<512, 512, 0, stream>>>(S, Wt0, b0, bufA);
  conv_kernel<256, 2, 2, true, false><<<512, 512, 0, stream>>>(bufA, Wt1, b1, bufB);
  conv_kernel<256, 4, 2, true, false><<<512, 512, 0, stream>>>(bufB, Wt2, b2, bufA);
  conv_kernel<256, 1, 1, false, true><<<512, 512, 0, stream>>>(bufA, Wt3, bo, bufB);

  transpose_s<<<dim3(32, 32), 256, 0, stream>>>(S, ST);
  gchunk<<<dim3(32, 2, 16), 512, 0, stream>>>(bufB, ST, G0, G1);
  prefix_wfin<<<dim3(32, 2, 8), 256, 0, stream>>>(G0, G1, wfin);
  attn_chunk<<<dim3(32, 16), 512, 0, stream>>>(bufB, ST, G0, G1, probs);
}

// Round 11
// 192.698 us; speedup vs baseline: 1.0628x; 1.0383x over previous
//
#include <hip/hip_runtime.h>

using u16 = unsigned short;
using u32 = unsigned int;
using short8 = __attribute__((ext_vector_type(8))) short;
using short4v = __attribute__((ext_vector_type(4))) short;
using bf16x8 = __attribute__((ext_vector_type(8))) __bf16;
using f32x4 = __attribute__((ext_vector_type(4))) float;

#define ALPHA_INV (1.0f / (128.0f * 100.0f))

__device__ __forceinline__ u32 swz(u32 off, u32 row) { return off ^ ((row & 7u) << 4); }

__device__ __forceinline__ u16 f2bf(float x) {
  u32 u = __float_as_uint(x);
  u32 r = u + 0x7fffu + ((u >> 16) & 1u);
  return (u16)(r >> 16);
}

__device__ __forceinline__ float bf2f(u16 x) {
  u32 u = ((u32)x) << 16;
  return __uint_as_float(u);
}

__device__ __forceinline__ f32x4 mfma(bf16x8 a, bf16x8 b, f32x4 c) {
  return __builtin_amdgcn_mfma_f32_16x16x32_bf16(a, b, c, 0, 0, 0);
}

// async 16B global->LDS; LDS dest is wave-uniform base + lane*16
__device__ __forceinline__ void gl16(const void* g, void* l) {
  __builtin_amdgcn_global_load_lds(
      (const __attribute__((address_space(1))) unsigned int*)g,
      (__attribute__((address_space(3))) unsigned int*)l, 16, 0, 0);
}

// ---------------------------------------------------------------------------
// All 4 weight tensors: transpose + bf16 + PRE-SWIZZLE in ONE launch.
// ---------------------------------------------------------------------------
__global__ void wtrans_all(const float* __restrict__ w0, const float* __restrict__ w1,
                           const float* __restrict__ w2, const float* __restrict__ wo,
                           u16* __restrict__ o0, u16* __restrict__ o1,
                           u16* __restrict__ o2, u16* __restrict__ o3) {
  int blk = blockIdx.x;
  const float* w; u16* o; int cin;
  if (blk < 256)       { w = w0; o = o0; cin = 128; }
  else if (blk < 768)  { w = w1; o = o1; cin = 256; blk -= 256; }
  else if (blk < 1280) { w = w2; o = o2; cin = 256; blk -= 768; }
  else                 { w = wo; o = o3; cin = 256; blk -= 1280; }
  int idx = blk * 256 + threadIdx.x;
  int row = idx >> 8, n = idx & 255;
  int tap = row / cin, c = row - tap * cin;
  int kc = c >> 6, ci = c & 63;
  u32 sb = (u32)(ci * 2) ^ ((u32)(n & 7) << 4);
  o[((size_t)tap * 256 + n) * cin + kc * 64 + (sb >> 1)] = f2bf(w[idx]);
}

// ---------------------------------------------------------------------------
// batch fp32 [B*T][128] -> ST [B][128][2048] bf16 (normal layout).
// ---------------------------------------------------------------------------
__global__ __launch_bounds__(256) void transpose_s(const float* __restrict__ X,
                                                   u16* __restrict__ ST) {
  __shared__ u16 L[64 * 129];
  const int tid = threadIdx.x;
  const int t0 = blockIdx.x * 64;
  const int b = blockIdx.y;
  const float* src = X + ((size_t)b * 2048 + t0) * 128;
#pragma unroll
  for (int it = 0; it < 4; ++it) {
    int s = tid + it * 256;
    int t = s >> 4, c8 = s & 15;
    float4 v0 = *(const float4*)(src + t * 128 + c8 * 8);
    float4 v1 = *(const float4*)(src + t * 128 + c8 * 8 + 4);
    u16* p = &L[t * 129 + c8 * 8];
    p[0] = f2bf(v0.x); p[1] = f2bf(v0.y); p[2] = f2bf(v0.z); p[3] = f2bf(v0.w);
    p[4] = f2bf(v1.x); p[5] = f2bf(v1.y); p[6] = f2bf(v1.z); p[7] = f2bf(v1.w);
  }
  __syncthreads();
  u16* dst = ST + (size_t)b * 128 * 2048 + t0;
#pragma unroll
  for (int it = 0; it < 4; ++it) {
    int s = tid + it * 256;
    int oct = s & 7, d = s >> 3;
    short8 v;
#pragma unroll
    for (int j = 0; j < 8; ++j) v[j] = (short)L[(oct * 8 + j) * 129 + d];
    *(short8*)(dst + (size_t)d * 2048 + oct * 8) = v;
  }
}

// ---------------------------------------------------------------------------
// conv_first: CIN=128, 2 taps, dil=1, ReLU. Input = fp32 batch (direct).
// A reg-staged with in-flight bf16 convert (same LDS image as gload of
// pre-swizzled data); B via global_load_lds. Output pre-swizzled bf16.
// ---------------------------------------------------------------------------
__global__ __launch_bounds__(512) void conv_first(
    const float* __restrict__ in, const u16* __restrict__ wt,
    const float* __restrict__ bias, u16* __restrict__ out) {
  constexpr int CIN = 128, BN = 256;
  __shared__ alignas(16) u16 Al[128 * 64];
  __shared__ alignas(16) u16 Bl[256 * 64];

  const int tid = threadIdx.x;
  const int wid = tid >> 6, lane = tid & 63;
  const int wr = wid >> 2, wc = wid & 3;
  const int lg = lane >> 4, lq = lane & 15;
  const int row0 = blockIdx.x * 128;
  const int tloc0 = row0 & 2047;

  f32x4 acc[4][4];
#pragma unroll
  for (int i = 0; i < 4; ++i)
#pragma unroll
    for (int j = 0; j < 4; ++j) acc[i][j] = (f32x4)0.0f;

#pragma unroll
  for (int tap = 0; tap < 2; ++tap) {
    const int shift = 1 - tap;
#pragma unroll
    for (int kc = 0; kc < 2; ++kc) {
      // A: fp32 load + convert + swizzled LDS write (key = global row & 7)
#pragma unroll
      for (int it = 0; it < 2; ++it) {
        int gi = tid + it * 512;
        int r = gi >> 3, cg = gi & 7;
        short8 v = (short8)0;
        if (!(tloc0 == 0 && r < shift)) {
          const float* src = in + (size_t)(row0 + r - shift) * CIN + kc * 64 + cg * 8;
          float4 a = *(const float4*)src;
          float4 b2 = *(const float4*)(src + 4);
          v[0] = (short)f2bf(a.x);  v[1] = (short)f2bf(a.y);
          v[2] = (short)f2bf(a.z);  v[3] = (short)f2bf(a.w);
          v[4] = (short)f2bf(b2.x); v[5] = (short)f2bf(b2.y);
          v[6] = (short)f2bf(b2.z); v[7] = (short)f2bf(b2.w);
        }
        *(short8*)((char*)Al + swz(r * 128 + cg * 16, (u32)(r - shift + 8))) = v;
      }
      // B: gload_lds of pre-swizzled weights
      {
        const u16* wtb = wt + ((size_t)(tap * 256)) * CIN + kc * 64;
#pragma unroll
        for (int it = 0; it < 4; ++it) {
          int gi = tid + it * 512;
          int n = gi >> 3, cg = gi & 7;
          gl16(wtb + (size_t)n * CIN + cg * 8, (char*)Bl + it * 8192 + wid * 1024);
        }
      }
      __syncthreads();
#pragma unroll
      for (int ks = 0; ks < 2; ++ks) {
        bf16x8 af[4], bfr[4];
#pragma unroll
        for (int mi = 0; mi < 4; ++mi) {
          int r = wr * 64 + mi * 16 + lq;
          af[mi] = *(const bf16x8*)((const char*)Al +
                                    swz(r * 128 + ks * 64 + lg * 16, (u32)(r - shift + 8)));
        }
#pragma unroll
        for (int ni = 0; ni < 4; ++ni) {
          int n = wc * 64 + ni * 16 + lq;
          bfr[ni] = *(const bf16x8*)((const char*)Bl + swz(n * 128 + ks * 64 + lg * 16, n));
        }
#pragma unroll
        for (int mi = 0; mi < 4; ++mi)
#pragma unroll
          for (int ni = 0; ni < 4; ++ni)
            acc[mi][ni] = mfma(af[mi], bfr[ni], acc[mi][ni]);
      }
      __syncthreads();
    }
  }

  float bcol[4];
#pragma unroll
  for (int ni = 0; ni < 4; ++ni) bcol[ni] = bias[wc * 64 + ni * 16 + lq];
#pragma unroll
  for (int mi = 0; mi < 4; ++mi)
#pragma unroll
    for (int ni = 0; ni < 4; ++ni)
#pragma unroll
      for (int rr = 0; rr < 4; ++rr) {
        float v = fmaxf(acc[mi][ni][rr] + bcol[ni], 0.0f);
        int row = row0 + wr * 64 + mi * 16 + lg * 4 + rr;
        int col = wc * 64 + ni * 16 + lq;
        int ci = col & 63;
        u32 sb = (u32)(ci * 2) ^ ((u32)(row & 7) << 4);
        out[(size_t)row * BN + wc * 64 + (sb >> 1)] = f2bf(v);
      }
}

// ---------------------------------------------------------------------------
// conv_mid<DIL>: CIN=256, 2 taps, ReLU. A-UNION staging: one A tile of
// 128+DIL rows (<=136) per kc serves both taps at shifted LDS rows.
// Boundary blocks zero rows < DIL after staging (block-uniform).
// ---------------------------------------------------------------------------
template <int DIL>
__global__ __launch_bounds__(512) void conv_mid(
    const u16* __restrict__ in, const u16* __restrict__ wt,
    const float* __restrict__ bias, u16* __restrict__ out) {
  constexpr int CIN = 256, BN = 256;
  __shared__ alignas(16) u16 Al[136 * 64];
  __shared__ alignas(16) u16 Bl[256 * 64];

  const int tid = threadIdx.x;
  const int wid = tid >> 6, lane = tid & 63;
  const int wr = wid >> 2, wc = wid & 3;
  const int lg = lane >> 4, lq = lane & 15;
  const int row0 = blockIdx.x * 128;
  const int tloc0 = row0 & 2047;

  f32x4 acc[4][4];
#pragma unroll
  for (int i = 0; i < 4; ++i)
#pragma unroll
    for (int j = 0; j < 4; ++j) acc[i][j] = (f32x4)0.0f;

#pragma unroll
  for (int kc = 0; kc < 4; ++kc) {
    // A union: LDS row L holds global row (row0 - DIL + L), pre-swizzled image
#pragma unroll
    for (int p = 0; p < 2; ++p) {
      int gi = tid + p * 512;
      int r = gi >> 3, cg = gi & 7;
      gl16(in + (size_t)(row0 - DIL + r) * CIN + kc * 64 + cg * 8,
           (char*)Al + p * 8192 + wid * 1024);
    }
    if (wid == 0)
      gl16(in + (size_t)(row0 - DIL + 128 + (lane >> 3)) * CIN + kc * 64 + (lane & 7) * 8,
           (char*)Al + 16384);
    // B tap0
    {
      const u16* wtb = wt + (size_t)0 * 256 * CIN + kc * 64;
#pragma unroll
      for (int p = 0; p < 4; ++p) {
        int gi = tid + p * 512;
        int n = gi >> 3, cg = gi & 7;
        gl16(wtb + (size_t)n * CIN + cg * 8, (char*)Bl + p * 8192 + wid * 1024);
      }
    }
    __syncthreads();
    if (tloc0 == 0) {  // zero garbage rows L < DIL (block-uniform)
      if (tid < DIL * 8) *(short8*)((char*)Al + tid * 16) = (short8)0;
      __syncthreads();
    }
    // tap0 (shift=DIL): LDS row = r, key = (r - DIL) & 7
#pragma unroll
    for (int ks = 0; ks < 2; ++ks) {
      bf16x8 af[4], bfr[4];
#pragma unroll
      for (int mi = 0; mi < 4; ++mi) {
        int r = wr * 64 + mi * 16 + lq;
        af[mi] = *(const bf16x8*)((const char*)Al +
                                  swz(r * 128 + ks * 64 + lg * 16, (u32)(r - DIL + 8)));
      }
#pragma unroll
      for (int ni = 0; ni < 4; ++ni) {
        int n = wc * 64 + ni * 16 + lq;
        bfr[ni] = *(const bf16x8*)((const char*)Bl + swz(n * 128 + ks * 64 + lg * 16, n));
      }
#pragma unroll
      for (int mi = 0; mi < 4; ++mi)
#pragma unroll
        for (int ni = 0; ni < 4; ++ni)
          acc[mi][ni] = mfma(af[mi], bfr[ni], acc[mi][ni]);
    }
    __syncthreads();
    // B tap1 restage (Al untouched)
    {
      const u16* wtb = wt + (size_t)1 * 256 * CIN + kc * 64;
#pragma unroll
      for (int p = 0; p < 4; ++p) {
        int gi = tid + p * 512;
        int n = gi >> 3, cg = gi & 7;
        gl16(wtb + (size_t)n * CIN + cg * 8, (char*)Bl + p * 8192 + wid * 1024);
      }
    }
    __syncthreads();
    // tap1 (shift=0): LDS row = r + DIL, key = r & 7
#pragma unroll
    for (int ks = 0; ks < 2; ++ks) {
      bf16x8 af[4], bfr[4];
#pragma unroll
      for (int mi = 0; mi < 4; ++mi) {
        int r = wr * 64 + mi * 16 + lq;
        af[mi] = *(const bf16x8*)((const char*)Al +
                                  swz((r + DIL) * 128 + ks * 64 + lg * 16, (u32)(r + 8)));
      }
#pragma unroll
      for (int ni = 0; ni < 4; ++ni) {
        int n = wc * 64 + ni * 16 + lq;
        bfr[ni] = *(const bf16x8*)((const char*)Bl + swz(n * 128 + ks * 64 + lg * 16, n));
      }
#pragma unroll
      for (int mi = 0; mi < 4; ++mi)
#pragma unroll
        for (int ni = 0; ni < 4; ++ni)
          acc[mi][ni] = mfma(af[mi], bfr[ni], acc[mi][ni]);
    }
    __syncthreads();
  }

  float bcol[4];
#pragma unroll
  for (int ni = 0; ni < 4; ++ni) bcol[ni] = bias[wc * 64 + ni * 16 + lq];
#pragma unroll
  for (int mi = 0; mi < 4; ++mi)
#pragma unroll
    for (int ni = 0; ni < 4; ++ni)
#pragma unroll
      for (int rr = 0; rr < 4; ++rr) {
        float v = fmaxf(acc[mi][ni][rr] + bcol[ni], 0.0f);
        int row = row0 + wr * 64 + mi * 16 + lg * 4 + rr;
        int col = wc * 64 + ni * 16 + lq;
        int ci = col & 63;
        u32 sb = (u32)(ci * 2) ^ ((u32)(row & 7) << 4);
        out[(size_t)row * BN + wc * 64 + (sb >> 1)] = f2bf(v);
      }
}

// ---------------------------------------------------------------------------
// conv_last: CIN=256, 1 tap, fused softmax. (R10-proven structure.)
// ---------------------------------------------------------------------------
__global__ __launch_bounds__(512) void conv_last(
    const u16* __restrict__ in, const u16* __restrict__ wt,
    const float* __restrict__ bias, u16* __restrict__ out) {
  constexpr int CIN = 256, BN = 256;
  __shared__ alignas(16) u16 Al[128 * 64];
  __shared__ alignas(16) u16 Bl[256 * 64];
  __shared__ float redA[4][128];
  __shared__ float redB[4][128];

  const int tid = threadIdx.x;
  const int wid = tid >> 6, lane = tid & 63;
  const int wr = wid >> 2, wc = wid & 3;
  const int lg = lane >> 4, lq = lane & 15;
  const int row0 = blockIdx.x * 128;

  f32x4 acc[4][4];
#pragma unroll
  for (int i = 0; i < 4; ++i)
#pragma unroll
    for (int j = 0; j < 4; ++j) acc[i][j] = (f32x4)0.0f;

#pragma unroll
  for (int kc = 0; kc < 4; ++kc) {
#pragma unroll
    for (int it = 0; it < 2; ++it) {
      int gi = tid + it * 512;
      int r = gi >> 3, cg = gi & 7;
      gl16(in + (size_t)(row0 + r) * CIN + kc * 64 + cg * 8,
           (char*)Al + it * 8192 + wid * 1024);
    }
    {
      const u16* wtb = wt + kc * 64;
#pragma unroll
      for (int it = 0; it < 4; ++it) {
        int gi = tid + it * 512;
        int n = gi >> 3, cg = gi & 7;
        gl16(wtb + (size_t)n * CIN + cg * 8, (char*)Bl + it * 8192 + wid * 1024);
      }
    }
    __syncthreads();
#pragma unroll
    for (int ks = 0; ks < 2; ++ks) {
      bf16x8 af[4], bfr[4];
#pragma unroll
      for (int mi = 0; mi < 4; ++mi) {
        int r = wr * 64 + mi * 16 + lq;
        af[mi] = *(const bf16x8*)((const char*)Al +
                                  swz(r * 128 + ks * 64 + lg * 16, (u32)(r + 8)));
      }
#pragma unroll
      for (int ni = 0; ni < 4; ++ni) {
        int n = wc * 64 + ni * 16 + lq;
        bfr[ni] = *(const bf16x8*)((const char*)Bl + swz(n * 128 + ks * 64 + lg * 16, n));
      }
#pragma unroll
      for (int mi = 0; mi < 4; ++mi)
#pragma unroll
        for (int ni = 0; ni < 4; ++ni)
          acc[mi][ni] = mfma(af[mi], bfr[ni], acc[mi][ni]);
    }
    __syncthreads();
  }

  float bcol[4];
#pragma unroll
  for (int ni = 0; ni < 4; ++ni) bcol[ni] = bias[wc * 64 + ni * 16 + lq];
#pragma unroll
  for (int mi = 0; mi < 4; ++mi)
#pragma unroll
    for (int ni = 0; ni < 4; ++ni)
#pragma unroll
      for (int rr = 0; rr < 4; ++rr) acc[mi][ni][rr] += bcol[ni];

  float tmx[4][4];
#pragma unroll
  for (int mi = 0; mi < 4; ++mi)
#pragma unroll
    for (int rr = 0; rr < 4; ++rr) {
      float v = fmaxf(fmaxf(acc[mi][0][rr], acc[mi][1][rr]),
                      fmaxf(acc[mi][2][rr], acc[mi][3][rr]));
#pragma unroll
      for (int off = 1; off < 16; off <<= 1) v = fmaxf(v, __shfl_xor(v, off));
      if (lq == 0) redA[wc][wr * 64 + mi * 16 + lg * 4 + rr] = v;
    }
  __syncthreads();
#pragma unroll
  for (int mi = 0; mi < 4; ++mi)
#pragma unroll
    for (int rr = 0; rr < 4; ++rr) {
      int rb = wr * 64 + mi * 16 + lg * 4 + rr;
      tmx[mi][rr] = fmaxf(fmaxf(redA[0][rb], redA[1][rb]),
                          fmaxf(redA[2][rb], redA[3][rb]));
    }
#pragma unroll
  for (int mi = 0; mi < 4; ++mi)
#pragma unroll
    for (int rr = 0; rr < 4; ++rr) {
      float s = 0.0f;
#pragma unroll
      for (int ni = 0; ni < 4; ++ni) {
        float p = __expf(acc[mi][ni][rr] - tmx[mi][rr]);
        acc[mi][ni][rr] = p;
        s += p;
      }
#pragma unroll
      for (int off = 1; off < 16; off <<= 1) s += __shfl_xor(s, off);
      if (lq == 0) redB[wc][wr * 64 + mi * 16 + lg * 4 + rr] = s;
    }
  __syncthreads();
#pragma unroll
  for (int mi = 0; mi < 4; ++mi)
#pragma unroll
    for (int rr = 0; rr < 4; ++rr) {
      int rb = wr * 64 + mi * 16 + lg * 4 + rr;
      float inv = 1.0f / (redB[0][rb] + redB[1][rb] + redB[2][rb] + redB[3][rb]);
      int row = row0 + rb;
#pragma unroll
      for (int ni = 0; ni < 4; ++ni) {
        int col = wc * 64 + ni * 16 + lq;
        out[(size_t)row * BN + col] = f2bf(acc[mi][ni][rr] * inv);
      }
    }
}

// ---------------------------------------------------------------------------
// gchunk (unchanged from R10)
// ---------------------------------------------------------------------------
__global__ __launch_bounds__(512) void gchunk(
    const u16* __restrict__ H, const u16* __restrict__ ST,
    u16* __restrict__ G0, u16* __restrict__ G1) {
  constexpr int M = 256, T = 2048;
  __shared__ alignas(16) u16 Hl[128 * 128];
  __shared__ alignas(16) u16 Sl[128 * 128];
  const int tid = threadIdx.x;
  const int wid = tid >> 6, lane = tid & 63;
  const int dg = wid >> 2, mg = wid & 3;
  const int lg = lane >> 4, lq = lane & 15;
  const int b = blockIdx.x, mh = blockIdx.y, j = blockIdx.z;
  u16* G = (mh == 0 ? G0 : G1);

#pragma unroll
  for (int it = 0; it < 4; ++it) {
    int s = tid + it * 512;
    int t = s >> 4, c8 = s & 15;
    short8 v = *(const short8*)(H + ((size_t)b * T + j * 128 + t) * M + mh * 128 + c8 * 8);
#pragma unroll
    for (int jj = 0; jj < 8; ++jj) {
      int ml = c8 * 8 + jj;
      *(u16*)((char*)Hl + swz(ml * 256 + t * 2, ml)) = (u16)v[jj];
    }
  }
#pragma unroll
  for (int it = 0; it < 4; ++it) {
    int s = tid + it * 512;
    int d = s >> 4, c8 = s & 15;
    *(short8*)((char*)Sl + swz(d * 256 + c8 * 16, d)) =
        *(const short8*)(ST + ((size_t)b * 128 + d) * T + j * 128 + c8 * 8);
  }
  __syncthreads();

  f32x4 acc[4][2];
#pragma unroll
  for (int di = 0; di < 4; ++di)
#pragma unroll
    for (int mi = 0; mi < 2; ++mi) acc[di][mi] = (f32x4)0.0f;

#pragma unroll
  for (int ks = 0; ks < 4; ++ks) {
    bf16x8 sfrag[4];
#pragma unroll
    for (int di = 0; di < 4; ++di) {
      int d = dg * 64 + di * 16 + lq;
      sfrag[di] = *(const bf16x8*)((const char*)Sl + swz(d * 256 + ks * 64 + lg * 16, d));
    }
#pragma unroll
    for (int mi = 0; mi < 2; ++mi) {
      int ml = mg * 32 + mi * 16 + lq;
      bf16x8 hfrag =
          *(const bf16x8*)((const char*)Hl + swz(ml * 256 + ks * 64 + lg * 16, ml));
#pragma unroll
      for (int di = 0; di < 4; ++di) acc[di][mi] = mfma(sfrag[di], hfrag, acc[di][mi]);
    }
  }

  u16* Gj = G + (((size_t)b * 16 + j) << 14);
#pragma unroll
  for (int di = 0; di < 4; ++di)
#pragma unroll
    for (int mi = 0; mi < 2; ++mi)
#pragma unroll
      for (int rr = 0; rr < 4; ++rr) {
        int d = dg * 64 + di * 16 + lg * 4 + rr;
        int ml = mg * 32 + mi * 16 + lq;
        Gj[d * 128 + ml] = f2bf(acc[di][mi][rr]);
      }
}

// ---------------------------------------------------------------------------
// prefix_wfin (unchanged from R10)
// ---------------------------------------------------------------------------
__global__ __launch_bounds__(256) void prefix_wfin(
    u16* __restrict__ G0, u16* __restrict__ G1, float* __restrict__ wfin) {
  __shared__ float Wl[16][132];
  const int b = blockIdx.x, mh = blockIdx.y, ds = blockIdx.z;
  u16* G = mh ? G1 : G0;
  const int tid = threadIdx.x;
  const int mo = tid & 15, dg = tid >> 4;
  const int d = ds * 16 + dg;
  size_t base = (((size_t)b * 16) << 14) + d * 128 + mo * 8;
  float acc[8];
#pragma unroll
  for (int k = 0; k < 8; ++k) acc[k] = ALPHA_INV;
  for (int j = 0; j < 16; ++j) {
    u16* p = G + base + ((size_t)j << 14);
    short8 g = *(short8*)p;
    short8 c;
#pragma unroll
    for (int k = 0; k < 8; ++k) c[k] = (short)f2bf(acc[k]);
    *(short8*)p = c;
#pragma unroll
    for (int k = 0; k < 8; ++k) acc[k] += bf2f((u16)g[k]);
  }
#pragma unroll
  for (int k = 0; k < 8; ++k) Wl[dg][mo * 8 + k] = acc[k];
  __syncthreads();
  const int ml = tid >> 1, dq = tid & 1;
  const int dl0 = dq * 8;
  float* dst = wfin + ((size_t)b * 256 + mh * 128 + ml) * 128 + ds * 16 + dl0;
  float4 v0 = make_float4(Wl[dl0][ml], Wl[dl0 + 1][ml], Wl[dl0 + 2][ml], Wl[dl0 + 3][ml]);
  float4 v1 = make_float4(Wl[dl0 + 4][ml], Wl[dl0 + 5][ml], Wl[dl0 + 6][ml], Wl[dl0 + 7][ml]);
  *(float4*)dst = v0;
  *(float4*)(dst + 4) = v1;
}

// ---------------------------------------------------------------------------
// attn_chunk (unchanged from R10)
// ---------------------------------------------------------------------------
__global__ __launch_bounds__(512) void attn_chunk(
    const u16* __restrict__ H, const u16* __restrict__ ST,
    const u16* __restrict__ C0, const u16* __restrict__ C1,
    float* __restrict__ out) {
  constexpr int M = 256, D = 128, T = 2048;
  __shared__ alignas(16) u16 Hi[128 * 256];
  __shared__ alignas(16) u16 Sl[128 * 128];
  __shared__ alignas(16) u16 Ct[128 * 128];

  const int tid = threadIdx.x;
  const int wid = tid >> 6, lane = tid & 63;
  const int lg = lane >> 4, lq = lane & 15;
  const int b = blockIdx.x, i = blockIdx.y;
  const size_t hrow0 = (size_t)b * T + i * 128;
  const size_t coff = ((size_t)b * 16 + i) * (128 * 128);

  bf16x8 aq[8];
  {
    const u16* qrow = H + (hrow0 + wid * 16 + lq) * M;
#pragma unroll
    for (int ks = 0; ks < 8; ++ks) aq[ks] = *(const bf16x8*)(qrow + ks * 32 + lg * 8);
  }

  short8 ct1r[4];
#pragma unroll
  for (int it = 0; it < 4; ++it) {
    int s = tid + it * 512;
    int d = s >> 4, c8 = s & 15;
    ct1r[it] = *(const short8*)(C1 + coff + d * 128 + c8 * 8);
  }

#pragma unroll
  for (int it = 0; it < 8; ++it) {
    int s = tid + it * 512;
    int r = s >> 5, c = s & 31;
    *(short8*)((char*)Hi + swz(r * 512 + c * 16, r)) =
        *(const short8*)(H + (hrow0 + r) * M + c * 8);
  }
#pragma unroll
  for (int it = 0; it < 4; ++it) {
    int s = tid + it * 512;
    int d = s >> 4, c8 = s & 15;
    *(short8*)((char*)Sl + swz(d * 256 + c8 * 16, d)) =
        *(const short8*)(ST + ((size_t)b * D + d) * T + i * 128 + c8 * 8);
  }
#pragma unroll
  for (int it = 0; it < 4; ++it) {
    int s = tid + it * 512;
    int d = s >> 4, c8 = s & 15;
    *(short8*)((char*)Ct + swz(d * 256 + c8 * 16, d)) = *(const short8*)(C0 + coff + d * 128 + c8 * 8);
  }
  __syncthreads();

  f32x4 accO[8];
#pragma unroll
  for (int df = 0; df < 8; ++df) accO[df] = (f32x4)0.0f;

#pragma unroll
  for (int ks = 0; ks < 4; ++ks)
#pragma unroll
    for (int df = 0; df < 8; ++df) {
      int d = df * 16 + lq;
      bf16x8 bf = *(const bf16x8*)((const char*)Ct + swz(d * 256 + ks * 64 + lg * 16, d));
      accO[df] = mfma(aq[ks], bf, accO[df]);
    }
  __syncthreads();
#pragma unroll
  for (int it = 0; it < 4; ++it) {
    int s = tid + it * 512;
    int d = s >> 4, c8 = s & 15;
    *(short8*)((char*)Ct + swz(d * 256 + c8 * 16, d)) = ct1r[it];
  }
  __syncthreads();
#pragma unroll
  for (int ks = 0; ks < 4; ++ks)
#pragma unroll
    for (int df = 0; df < 8; ++df) {
      int d = df * 16 + lq;
      bf16x8 bf = *(const bf16x8*)((const char*)Ct + swz(d * 256 + ks * 64 + lg * 16, d));
      accO[df] = mfma(aq[4 + ks], bf, accO[df]);
    }
  __syncthreads();

  f32x4 accP[8];
#pragma unroll
  for (int cf = 0; cf < 8; ++cf) accP[cf] = (f32x4)0.0f;
#pragma unroll
  for (int ks = 0; ks < 8; ++ks)
#pragma unroll
    for (int cf = 0; cf < 8; ++cf) {
      int tt = cf * 16 + lq;
      bf16x8 bf = *(const bf16x8*)((const char*)Hi + swz(tt * 512 + ks * 64 + lg * 16, tt));
      accP[cf] = mfma(aq[ks], bf, accP[cf]);
    }
  char* Pw = (char*)Ct + wid * 4096;
#pragma unroll
  for (int cf = 0; cf < 8; ++cf)
#pragma unroll
    for (int rr = 0; rr < 4; ++rr) {
      int ql = lg * 4 + rr;
      int tl = cf * 16 + lq;
      float v = accP[cf][rr];
      if (tl >= wid * 16 + ql) v = 0.0f;
      *(u16*)(Pw + swz(ql * 256 + tl * 2, ql)) = f2bf(v);
    }
#pragma unroll
  for (int ks = 0; ks < 4; ++ks) {
    bf16x8 a = *(const bf16x8*)(Pw + swz(lq * 256 + ks * 64 + lg * 16, lq));
#pragma unroll
    for (int df = 0; df < 8; ++df) {
      int d = df * 16 + lq;
      bf16x8 bf = *(const bf16x8*)((const char*)Sl + swz(d * 256 + ks * 64 + lg * 16, d));
      accO[df] = mfma(a, bf, accO[df]);
    }
  }

#pragma unroll
  for (int rr = 0; rr < 4; ++rr) {
    float ssum = 0.0f;
#pragma unroll
    for (int df = 0; df < 8; ++df) ssum += accO[df][rr];
#pragma unroll
    for (int off = 1; off < 16; off <<= 1) ssum += __shfl_xor(ssum, off);
    float inv = 1.0f / ssum;
    size_t row = hrow0 + wid * 16 + lg * 4 + rr;
#pragma unroll
    for (int df = 0; df < 8; ++df)
      out[row * D + df * 16 + lq] = accO[df][rr] * inv;
  }
}

// ---------------------------------------------------------------------------
extern "C" void kernel_launch(void* const* d_in, const int* in_sizes, int n_in,
                              void* d_out, int out_size, void* d_ws, size_t ws_size,
                              hipStream_t stream) {
  const float* batch = (const float*)d_in[0];
  const float* w0 = (const float*)d_in[1];
  const float* b0 = (const float*)d_in[2];
  const float* w1 = (const float*)d_in[3];
  const float* b1 = (const float*)d_in[4];
  const float* w2 = (const float*)d_in[5];
  const float* b2 = (const float*)d_in[6];
  const float* wo = (const float*)d_in[7];
  const float* bo = (const float*)d_in[8];

  const size_t SZ_S = 16777216;     // 16MB
  const size_t SZ_BUF = 33554432;   // 32MB
  const size_t NEED = SZ_S + 2 * SZ_BUF + 786432;
  if (ws_size < NEED) return;

  char* ws = (char*)d_ws;
  // Layout:
  //  [0,16M):   G0/C0
  //  [16M,48M): bufA (conv0/conv2 out; dead after conv3) -> lower 16M = ST, upper = G1/C1
  //  [48M,80M): bufB = H (live to end)
  //  [80M,..):  weights
  u16* bufA = (u16*)(ws + SZ_S);
  u16* bufB = (u16*)(ws + SZ_S + SZ_BUF);
  u16* Wt0 = (u16*)(ws + SZ_S + 2 * SZ_BUF);
  u16* Wt1 = Wt0 + 2 * 256 * 128;
  u16* Wt2 = Wt1 + 2 * 256 * 256;
  u16* Wt3 = Wt2 + 2 * 256 * 256;
  u16* ST = bufA;
  u16* G0 = (u16*)ws;
  u16* G1 = (u16*)(ws + 2 * SZ_S);
  float* probs = (float*)d_out;
  float* wfin = probs + (size_t)32 * 2048 * 128;

  wtrans_all<<<1536, 256, 0, stream>>>(w0, w1, w2, wo, Wt0, Wt1, Wt2, Wt3);

  conv_first<<<512, 512, 0, stream>>>(batch, Wt0, b0, bufA);
  conv_mid<2><<<512, 512, 0, stream>>>(bufA, Wt1, b1, bufB);
  conv_mid<4><<<512, 512, 0, stream>>>(bufB, Wt2, b2, bufA);
  conv_last<<<512, 512, 0, stream>>>(bufA, Wt3, bo, bufB);

  transpose_s<<<dim3(32, 32), 256, 0, stream>>>(batch, ST);
  gchunk<<<dim3(32, 2, 16), 512, 0, stream>>>(bufB, ST, G0, G1);
  prefix_wfin<<<dim3(32, 2, 8), 256, 0, stream>>>(G0, G1, wfin);
  attn_chunk<<<dim3(32, 16), 512, 0, stream>>>(bufB, ST, G0, G1, probs);
}

// Round 13
// 190.735 us; speedup vs baseline: 1.0737x; 1.0103x over previous
//
#include <hip/hip_runtime.h>

using u16 = unsigned short;
using u32 = unsigned int;
using short8 = __attribute__((ext_vector_type(8))) short;
using short4v = __attribute__((ext_vector_type(4))) short;
using bf16x8 = __attribute__((ext_vector_type(8))) __bf16;
using f32x4 = __attribute__((ext_vector_type(4))) float;

#define ALPHA_INV (1.0f / (128.0f * 100.0f))

__device__ __forceinline__ u32 swz(u32 off, u32 row) { return off ^ ((row & 7u) << 4); }

__device__ __forceinline__ u16 f2bf(float x) {
  u32 u = __float_as_uint(x);
  u32 r = u + 0x7fffu + ((u >> 16) & 1u);
  return (u16)(r >> 16);
}

__device__ __forceinline__ float bf2f(u16 x) {
  u32 u = ((u32)x) << 16;
  return __uint_as_float(u);
}

__device__ __forceinline__ f32x4 mfma(bf16x8 a, bf16x8 b, f32x4 c) {
  return __builtin_amdgcn_mfma_f32_16x16x32_bf16(a, b, c, 0, 0, 0);
}

// async 16B global->LDS; LDS dest is wave-uniform base + lane*16
__device__ __forceinline__ void gl16(const void* g, void* l) {
  __builtin_amdgcn_global_load_lds(
      (const __attribute__((address_space(1))) unsigned int*)g,
      (__attribute__((address_space(3))) unsigned int*)l, 16, 0, 0);
}

// ---------------------------------------------------------------------------
// prep: (a) 4 weight tensors transpose+bf16+pre-swizzle; (b) batch fp32 ->
// ST [B][128][2048] bf16 (ST in its OWN region, not clobbered by convs).
// ---------------------------------------------------------------------------
__global__ __launch_bounds__(256) void prep(
    const float* __restrict__ batch,
    const float* __restrict__ w0, const float* __restrict__ w1,
    const float* __restrict__ w2, const float* __restrict__ wo,
    u16* __restrict__ o0, u16* __restrict__ o1,
    u16* __restrict__ o2, u16* __restrict__ o3,
    u16* __restrict__ ST) {
  __shared__ u16 L[64 * 129];
  int blk = blockIdx.x;
  if (blk < 1536) {
    const float* w; u16* o; int cin;
    if (blk < 256)       { w = w0; o = o0; cin = 128; }
    else if (blk < 768)  { w = w1; o = o1; cin = 256; blk -= 256; }
    else if (blk < 1280) { w = w2; o = o2; cin = 256; blk -= 768; }
    else                 { w = wo; o = o3; cin = 256; blk -= 1280; }
    int idx = blk * 256 + threadIdx.x;
    int row = idx >> 8, n = idx & 255;
    int tap = row / cin, c = row - tap * cin;
    int kc = c >> 6, ci = c & 63;
    u32 sb = (u32)(ci * 2) ^ ((u32)(n & 7) << 4);
    o[((size_t)tap * 256 + n) * cin + kc * 64 + (sb >> 1)] = f2bf(w[idx]);
    return;
  }
  blk -= 1536;
  const int tid = threadIdx.x;
  const int t0 = (blk & 31) * 64;
  const int b = blk >> 5;
  const float* src = batch + ((size_t)b * 2048 + t0) * 128;
#pragma unroll
  for (int it = 0; it < 4; ++it) {
    int s = tid + it * 256;
    int t = s >> 4, c8 = s & 15;
    float4 v0 = *(const float4*)(src + t * 128 + c8 * 8);
    float4 v1 = *(const float4*)(src + t * 128 + c8 * 8 + 4);
    u16* p = &L[t * 129 + c8 * 8];
    p[0] = f2bf(v0.x); p[1] = f2bf(v0.y); p[2] = f2bf(v0.z); p[3] = f2bf(v0.w);
    p[4] = f2bf(v1.x); p[5] = f2bf(v1.y); p[6] = f2bf(v1.z); p[7] = f2bf(v1.w);
  }
  __syncthreads();
  u16* dst = ST + (size_t)b * 128 * 2048 + t0;
#pragma unroll
  for (int it = 0; it < 4; ++it) {
    int s = tid + it * 256;
    int oct = s & 7, d = s >> 3;
    short8 v;
#pragma unroll
    for (int j = 0; j < 8; ++j) v[j] = (short)L[(oct * 8 + j) * 129 + d];
    *(short8*)(dst + (size_t)d * 2048 + oct * 8) = v;
  }
}

// ---------------------------------------------------------------------------
// conv_first: CIN=128, 2 taps, dil=1, ReLU. Input = fp32 batch (direct).
// ---------------------------------------------------------------------------
__global__ __launch_bounds__(512) void conv_first(
    const float* __restrict__ in, const u16* __restrict__ wt,
    const float* __restrict__ bias, u16* __restrict__ out) {
  constexpr int CIN = 128, BN = 256;
  __shared__ alignas(16) u16 Al[128 * 64];
  __shared__ alignas(16) u16 Bl[256 * 64];

  const int tid = threadIdx.x;
  const int wid = tid >> 6, lane = tid & 63;
  const int wr = wid >> 2, wc = wid & 3;
  const int lg = lane >> 4, lq = lane & 15;
  const int row0 = blockIdx.x * 128;
  const int tloc0 = row0 & 2047;

  f32x4 acc[4][4];
#pragma unroll
  for (int i = 0; i < 4; ++i)
#pragma unroll
    for (int j = 0; j < 4; ++j) acc[i][j] = (f32x4)0.0f;

#pragma unroll
  for (int tap = 0; tap < 2; ++tap) {
    const int shift = 1 - tap;
#pragma unroll
    for (int kc = 0; kc < 2; ++kc) {
#pragma unroll
      for (int it = 0; it < 2; ++it) {
        int gi = tid + it * 512;
        int r = gi >> 3, cg = gi & 7;
        short8 v = (short8)0;
        if (!(tloc0 == 0 && r < shift)) {
          const float* src = in + (size_t)(row0 + r - shift) * CIN + kc * 64 + cg * 8;
          float4 a = *(const float4*)src;
          float4 b2 = *(const float4*)(src + 4);
          v[0] = (short)f2bf(a.x);  v[1] = (short)f2bf(a.y);
          v[2] = (short)f2bf(a.z);  v[3] = (short)f2bf(a.w);
          v[4] = (short)f2bf(b2.x); v[5] = (short)f2bf(b2.y);
          v[6] = (short)f2bf(b2.z); v[7] = (short)f2bf(b2.w);
        }
        *(short8*)((char*)Al + swz(r * 128 + cg * 16, (u32)(r - shift + 8))) = v;
      }
      {
        const u16* wtb = wt + ((size_t)(tap * 256)) * CIN + kc * 64;
#pragma unroll
        for (int it = 0; it < 4; ++it) {
          int gi = tid + it * 512;
          int n = gi >> 3, cg = gi & 7;
          gl16(wtb + (size_t)n * CIN + cg * 8, (char*)Bl + it * 8192 + wid * 1024);
        }
      }
      __syncthreads();
#pragma unroll
      for (int ks = 0; ks < 2; ++ks) {
        bf16x8 af[4], bfr[4];
#pragma unroll
        for (int mi = 0; mi < 4; ++mi) {
          int r = wr * 64 + mi * 16 + lq;
          af[mi] = *(const bf16x8*)((const char*)Al +
                                    swz(r * 128 + ks * 64 + lg * 16, (u32)(r - shift + 8)));
        }
#pragma unroll
        for (int ni = 0; ni < 4; ++ni) {
          int n = wc * 64 + ni * 16 + lq;
          bfr[ni] = *(const bf16x8*)((const char*)Bl + swz(n * 128 + ks * 64 + lg * 16, n));
        }
#pragma unroll
        for (int mi = 0; mi < 4; ++mi)
#pragma unroll
          for (int ni = 0; ni < 4; ++ni)
            acc[mi][ni] = mfma(af[mi], bfr[ni], acc[mi][ni]);
      }
      __syncthreads();
    }
  }

  float bcol[4];
#pragma unroll
  for (int ni = 0; ni < 4; ++ni) bcol[ni] = bias[wc * 64 + ni * 16 + lq];
#pragma unroll
  for (int mi = 0; mi < 4; ++mi)
#pragma unroll
    for (int ni = 0; ni < 4; ++ni)
#pragma unroll
      for (int rr = 0; rr < 4; ++rr) {
        float v = fmaxf(acc[mi][ni][rr] + bcol[ni], 0.0f);
        int row = row0 + wr * 64 + mi * 16 + lg * 4 + rr;
        int col = wc * 64 + ni * 16 + lq;
        int ci = col & 63;
        u32 sb = (u32)(ci * 2) ^ ((u32)(row & 7) << 4);
        out[(size_t)row * BN + wc * 64 + (sb >> 1)] = f2bf(v);
      }
}

// ---------------------------------------------------------------------------
// conv_mid<DIL>: CIN=256, 2 taps, ReLU. A-union staging (proven R11).
// ---------------------------------------------------------------------------
template <int DIL>
__global__ __launch_bounds__(512) void conv_mid(
    const u16* __restrict__ in, const u16* __restrict__ wt,
    const float* __restrict__ bias, u16* __restrict__ out) {
  constexpr int CIN = 256, BN = 256;
  __shared__ alignas(16) u16 Al[136 * 64];
  __shared__ alignas(16) u16 Bl[256 * 64];

  const int tid = threadIdx.x;
  const int wid = tid >> 6, lane = tid & 63;
  const int wr = wid >> 2, wc = wid & 3;
  const int lg = lane >> 4, lq = lane & 15;
  const int row0 = blockIdx.x * 128;
  const int tloc0 = row0 & 2047;

  f32x4 acc[4][4];
#pragma unroll
  for (int i = 0; i < 4; ++i)
#pragma unroll
    for (int j = 0; j < 4; ++j) acc[i][j] = (f32x4)0.0f;

#pragma unroll
  for (int kc = 0; kc < 4; ++kc) {
#pragma unroll
    for (int p = 0; p < 2; ++p) {
      int gi = tid + p * 512;
      int r = gi >> 3, cg = gi & 7;
      gl16(in + (size_t)(row0 - DIL + r) * CIN + kc * 64 + cg * 8,
           (char*)Al + p * 8192 + wid * 1024);
    }
    if (wid == 0)
      gl16(in + (size_t)(row0 - DIL + 128 + (lane >> 3)) * CIN + kc * 64 + (lane & 7) * 8,
           (char*)Al + 16384);
    {
      const u16* wtb = wt + (size_t)0 * 256 * CIN + kc * 64;
#pragma unroll
      for (int p = 0; p < 4; ++p) {
        int gi = tid + p * 512;
        int n = gi >> 3, cg = gi & 7;
        gl16(wtb + (size_t)n * CIN + cg * 8, (char*)Bl + p * 8192 + wid * 1024);
      }
    }
    __syncthreads();
    if (tloc0 == 0) {
      if (tid < DIL * 8) *(short8*)((char*)Al + tid * 16) = (short8)0;
      __syncthreads();
    }
#pragma unroll
    for (int ks = 0; ks < 2; ++ks) {
      bf16x8 af[4], bfr[4];
#pragma unroll
      for (int mi = 0; mi < 4; ++mi) {
        int r = wr * 64 + mi * 16 + lq;
        af[mi] = *(const bf16x8*)((const char*)Al +
                                  swz(r * 128 + ks * 64 + lg * 16, (u32)(r - DIL + 8)));
      }
#pragma unroll
      for (int ni = 0; ni < 4; ++ni) {
        int n = wc * 64 + ni * 16 + lq;
        bfr[ni] = *(const bf16x8*)((const char*)Bl + swz(n * 128 + ks * 64 + lg * 16, n));
      }
#pragma unroll
      for (int mi = 0; mi < 4; ++mi)
#pragma unroll
        for (int ni = 0; ni < 4; ++ni)
          acc[mi][ni] = mfma(af[mi], bfr[ni], acc[mi][ni]);
    }
    __syncthreads();
    {
      const u16* wtb = wt + (size_t)1 * 256 * CIN + kc * 64;
#pragma unroll
      for (int p = 0; p < 4; ++p) {
        int gi = tid + p * 512;
        int n = gi >> 3, cg = gi & 7;
        gl16(wtb + (size_t)n * CIN + cg * 8, (char*)Bl + p * 8192 + wid * 1024);
      }
    }
    __syncthreads();
#pragma unroll
    for (int ks = 0; ks < 2; ++ks) {
      bf16x8 af[4], bfr[4];
#pragma unroll
      for (int mi = 0; mi < 4; ++mi) {
        int r = wr * 64 + mi * 16 + lq;
        af[mi] = *(const bf16x8*)((const char*)Al +
                                  swz((r + DIL) * 128 + ks * 64 + lg * 16, (u32)(r + 8)));
      }
#pragma unroll
      for (int ni = 0; ni < 4; ++ni) {
        int n = wc * 64 + ni * 16 + lq;
        bfr[ni] = *(const bf16x8*)((const char*)Bl + swz(n * 128 + ks * 64 + lg * 16, n));
      }
#pragma unroll
      for (int mi = 0; mi < 4; ++mi)
#pragma unroll
        for (int ni = 0; ni < 4; ++ni)
          acc[mi][ni] = mfma(af[mi], bfr[ni], acc[mi][ni]);
    }
    __syncthreads();
  }

  float bcol[4];
#pragma unroll
  for (int ni = 0; ni < 4; ++ni) bcol[ni] = bias[wc * 64 + ni * 16 + lq];
#pragma unroll
  for (int mi = 0; mi < 4; ++mi)
#pragma unroll
    for (int ni = 0; ni < 4; ++ni)
#pragma unroll
      for (int rr = 0; rr < 4; ++rr) {
        float v = fmaxf(acc[mi][ni][rr] + bcol[ni], 0.0f);
        int row = row0 + wr * 64 + mi * 16 + lg * 4 + rr;
        int col = wc * 64 + ni * 16 + lq;
        int ci = col & 63;
        u32 sb = (u32)(ci * 2) ^ ((u32)(row & 7) << 4);
        out[(size_t)row * BN + wc * 64 + (sb >> 1)] = f2bf(v);
      }
}

// ---------------------------------------------------------------------------
// conv_last: CIN=256, 1 tap, fused softmax.
// ---------------------------------------------------------------------------
__global__ __launch_bounds__(512) void conv_last(
    const u16* __restrict__ in, const u16* __restrict__ wt,
    const float* __restrict__ bias, u16* __restrict__ out) {
  constexpr int CIN = 256, BN = 256;
  __shared__ alignas(16) u16 Al[128 * 64];
  __shared__ alignas(16) u16 Bl[256 * 64];
  __shared__ float redA[4][128];
  __shared__ float redB[4][128];

  const int tid = threadIdx.x;
  const int wid = tid >> 6, lane = tid & 63;
  const int wr = wid >> 2, wc = wid & 3;
  const int lg = lane >> 4, lq = lane & 15;
  const int row0 = blockIdx.x * 128;

  f32x4 acc[4][4];
#pragma unroll
  for (int i = 0; i < 4; ++i)
#pragma unroll
    for (int j = 0; j < 4; ++j) acc[i][j] = (f32x4)0.0f;

#pragma unroll
  for (int kc = 0; kc < 4; ++kc) {
#pragma unroll
    for (int it = 0; it < 2; ++it) {
      int gi = tid + it * 512;
      int r = gi >> 3, cg = gi & 7;
      gl16(in + (size_t)(row0 + r) * CIN + kc * 64 + cg * 8,
           (char*)Al + it * 8192 + wid * 1024);
    }
    {
      const u16* wtb = wt + kc * 64;
#pragma unroll
      for (int it = 0; it < 4; ++it) {
        int gi = tid + it * 512;
        int n = gi >> 3, cg = gi & 7;
        gl16(wtb + (size_t)n * CIN + cg * 8, (char*)Bl + it * 8192 + wid * 1024);
      }
    }
    __syncthreads();
#pragma unroll
    for (int ks = 0; ks < 2; ++ks) {
      bf16x8 af[4], bfr[4];
#pragma unroll
      for (int mi = 0; mi < 4; ++mi) {
        int r = wr * 64 + mi * 16 + lq;
        af[mi] = *(const bf16x8*)((const char*)Al +
                                  swz(r * 128 + ks * 64 + lg * 16, (u32)(r + 8)));
      }
#pragma unroll
      for (int ni = 0; ni < 4; ++ni) {
        int n = wc * 64 + ni * 16 + lq;
        bfr[ni] = *(const bf16x8*)((const char*)Bl + swz(n * 128 + ks * 64 + lg * 16, n));
      }
#pragma unroll
      for (int mi = 0; mi < 4; ++mi)
#pragma unroll
        for (int ni = 0; ni < 4; ++ni)
          acc[mi][ni] = mfma(af[mi], bfr[ni], acc[mi][ni]);
    }
    __syncthreads();
  }

  float bcol[4];
#pragma unroll
  for (int ni = 0; ni < 4; ++ni) bcol[ni] = bias[wc * 64 + ni * 16 + lq];
#pragma unroll
  for (int mi = 0; mi < 4; ++mi)
#pragma unroll
    for (int ni = 0; ni < 4; ++ni)
#pragma unroll
      for (int rr = 0; rr < 4; ++rr) acc[mi][ni][rr] += bcol[ni];

  float tmx[4][4];
#pragma unroll
  for (int mi = 0; mi < 4; ++mi)
#pragma unroll
    for (int rr = 0; rr < 4; ++rr) {
      float v = fmaxf(fmaxf(acc[mi][0][rr], acc[mi][1][rr]),
                      fmaxf(acc[mi][2][rr], acc[mi][3][rr]));
#pragma unroll
      for (int off = 1; off < 16; off <<= 1) v = fmaxf(v, __shfl_xor(v, off));
      if (lq == 0) redA[wc][wr * 64 + mi * 16 + lg * 4 + rr] = v;
    }
  __syncthreads();
#pragma unroll
  for (int mi = 0; mi < 4; ++mi)
#pragma unroll
    for (int rr = 0; rr < 4; ++rr) {
      int rb = wr * 64 + mi * 16 + lg * 4 + rr;
      tmx[mi][rr] = fmaxf(fmaxf(redA[0][rb], redA[1][rb]),
                          fmaxf(redA[2][rb], redA[3][rb]));
    }
#pragma unroll
  for (int mi = 0; mi < 4; ++mi)
#pragma unroll
    for (int rr = 0; rr < 4; ++rr) {
      float s = 0.0f;
#pragma unroll
      for (int ni = 0; ni < 4; ++ni) {
        float p = __expf(acc[mi][ni][rr] - tmx[mi][rr]);
        acc[mi][ni][rr] = p;
        s += p;
      }
#pragma unroll
      for (int off = 1; off < 16; off <<= 1) s += __shfl_xor(s, off);
      if (lq == 0) redB[wc][wr * 64 + mi * 16 + lg * 4 + rr] = s;
    }
  __syncthreads();
#pragma unroll
  for (int mi = 0; mi < 4; ++mi)
#pragma unroll
    for (int rr = 0; rr < 4; ++rr) {
      int rb = wr * 64 + mi * 16 + lg * 4 + rr;
      float inv = 1.0f / (redB[0][rb] + redB[1][rb] + redB[2][rb] + redB[3][rb]);
      int row = row0 + rb;
#pragma unroll
      for (int ni = 0; ni < 4; ++ni) {
        int col = wc * 64 + ni * 16 + lq;
        out[(size_t)row * BN + col] = f2bf(acc[mi][ni][rr] * inv);
      }
    }
}

// ---------------------------------------------------------------------------
// gchunk (unchanged)
// ---------------------------------------------------------------------------
__global__ __launch_bounds__(512) void gchunk(
    const u16* __restrict__ H, const u16* __restrict__ ST,
    u16* __restrict__ G0, u16* __restrict__ G1) {
  constexpr int M = 256, T = 2048;
  __shared__ alignas(16) u16 Hl[128 * 128];
  __shared__ alignas(16) u16 Sl[128 * 128];
  const int tid = threadIdx.x;
  const int wid = tid >> 6, lane = tid & 63;
  const int dg = wid >> 2, mg = wid & 3;
  const int lg = lane >> 4, lq = lane & 15;
  const int b = blockIdx.x, mh = blockIdx.y, j = blockIdx.z;
  u16* G = (mh == 0 ? G0 : G1);

#pragma unroll
  for (int it = 0; it < 4; ++it) {
    int s = tid + it * 512;
    int t = s >> 4, c8 = s & 15;
    short8 v = *(const short8*)(H + ((size_t)b * T + j * 128 + t) * M + mh * 128 + c8 * 8);
#pragma unroll
    for (int jj = 0; jj < 8; ++jj) {
      int ml = c8 * 8 + jj;
      *(u16*)((char*)Hl + swz(ml * 256 + t * 2, ml)) = (u16)v[jj];
    }
  }
#pragma unroll
  for (int it = 0; it < 4; ++it) {
    int s = tid + it * 512;
    int d = s >> 4, c8 = s & 15;
    *(short8*)((char*)Sl + swz(d * 256 + c8 * 16, d)) =
        *(const short8*)(ST + ((size_t)b * 128 + d) * T + j * 128 + c8 * 8);
  }
  __syncthreads();

  f32x4 acc[4][2];
#pragma unroll
  for (int di = 0; di < 4; ++di)
#pragma unroll
    for (int mi = 0; mi < 2; ++mi) acc[di][mi] = (f32x4)0.0f;

#pragma unroll
  for (int ks = 0; ks < 4; ++ks) {
    bf16x8 sfrag[4];
#pragma unroll
    for (int di = 0; di < 4; ++di) {
      int d = dg * 64 + di * 16 + lq;
      sfrag[di] = *(const bf16x8*)((const char*)Sl + swz(d * 256 + ks * 64 + lg * 16, d));
    }
#pragma unroll
    for (int mi = 0; mi < 2; ++mi) {
      int ml = mg * 32 + mi * 16 + lq;
      bf16x8 hfrag =
          *(const bf16x8*)((const char*)Hl + swz(ml * 256 + ks * 64 + lg * 16, ml));
#pragma unroll
      for (int di = 0; di < 4; ++di) acc[di][mi] = mfma(sfrag[di], hfrag, acc[di][mi]);
    }
  }

  u16* Gj = G + (((size_t)b * 16 + j) << 14);
#pragma unroll
  for (int di = 0; di < 4; ++di)
#pragma unroll
    for (int mi = 0; mi < 2; ++mi)
#pragma unroll
      for (int rr = 0; rr < 4; ++rr) {
        int d = dg * 64 + di * 16 + lg * 4 + rr;
        int ml = mg * 32 + mi * 16 + lq;
        Gj[d * 128 + ml] = f2bf(acc[di][mi][rr]);
      }
}

// ---------------------------------------------------------------------------
// prefix_wfin (unchanged)
// ---------------------------------------------------------------------------
__global__ __launch_bounds__(256) void prefix_wfin(
    u16* __restrict__ G0, u16* __restrict__ G1, float* __restrict__ wfin) {
  __shared__ float Wl[16][132];
  const int b = blockIdx.x, mh = blockIdx.y, ds = blockIdx.z;
  u16* G = mh ? G1 : G0;
  const int tid = threadIdx.x;
  const int mo = tid & 15, dg = tid >> 4;
  const int d = ds * 16 + dg;
  size_t base = (((size_t)b * 16) << 14) + d * 128 + mo * 8;
  float acc[8];
#pragma unroll
  for (int k = 0; k < 8; ++k) acc[k] = ALPHA_INV;
  for (int j = 0; j < 16; ++j) {
    u16* p = G + base + ((size_t)j << 14);
    short8 g = *(short8*)p;
    short8 c;
#pragma unroll
    for (int k = 0; k < 8; ++k) c[k] = (short)f2bf(acc[k]);
    *(short8*)p = c;
#pragma unroll
    for (int k = 0; k < 8; ++k) acc[k] += bf2f((u16)g[k]);
  }
#pragma unroll
  for (int k = 0; k < 8; ++k) Wl[dg][mo * 8 + k] = acc[k];
  __syncthreads();
  const int ml = tid >> 1, dq = tid & 1;
  const int dl0 = dq * 8;
  float* dst = wfin + ((size_t)b * 256 + mh * 128 + ml) * 128 + ds * 16 + dl0;
  float4 v0 = make_float4(Wl[dl0][ml], Wl[dl0 + 1][ml], Wl[dl0 + 2][ml], Wl[dl0 + 3][ml]);
  float4 v1 = make_float4(Wl[dl0 + 4][ml], Wl[dl0 + 5][ml], Wl[dl0 + 6][ml], Wl[dl0 + 7][ml]);
  *(float4*)dst = v0;
  *(float4*)(dst + 4) = v1;
}

// ---------------------------------------------------------------------------
// attn_chunk, 3 barriers, Hi staged from registers (audited R12 structure):
//  stage: Sl, Ct=C0 (global); Hi rows from aq (ds_write); C1 -> regs
//  sync; {num0 + QK^T + mask}  (96 MFMA)
//  sync; Ct <- C1 regs; P -> own-wave region of Hi (dead)
//  sync; {num1 + PV}           (64 MFMA); epilogue
// ---------------------------------------------------------------------------
__global__ __launch_bounds__(512) void attn_chunk(
    const u16* __restrict__ H, const u16* __restrict__ ST,
    const u16* __restrict__ C0, const u16* __restrict__ C1,
    float* __restrict__ out) {
  constexpr int M = 256, D = 128, T = 2048;
  __shared__ alignas(16) u16 Hi[128 * 256];
  __shared__ alignas(16) u16 Sl[128 * 128];
  __shared__ alignas(16) u16 Ct[128 * 128];

  const int tid = threadIdx.x;
  const int wid = tid >> 6, lane = tid & 63;
  const int lg = lane >> 4, lq = lane & 15;
  const int b = blockIdx.x, i = blockIdx.y;
  const size_t hrow0 = (size_t)b * T + i * 128;
  const size_t coff = ((size_t)b * 16 + i) * (128 * 128);

  bf16x8 aq[8];
  {
    const u16* qrow = H + (hrow0 + wid * 16 + lq) * M;
#pragma unroll
    for (int ks = 0; ks < 8; ++ks) aq[ks] = *(const bf16x8*)(qrow + ks * 32 + lg * 8);
  }

  short8 ct1r[4];
#pragma unroll
  for (int it = 0; it < 4; ++it) {
    int s = tid + it * 512;
    int d = s >> 4, c8 = s & 15;
    ct1r[it] = *(const short8*)(C1 + coff + d * 128 + c8 * 8);
  }

  {
    int r = wid * 16 + lq;
#pragma unroll
    for (int ks = 0; ks < 8; ++ks)
      *(short8*)((char*)Hi + swz(r * 512 + ks * 64 + lg * 16, r)) =
          __builtin_bit_cast(short8, aq[ks]);
  }
#pragma unroll
  for (int it = 0; it < 4; ++it) {
    int s = tid + it * 512;
    int d = s >> 4, c8 = s & 15;
    *(short8*)((char*)Sl + swz(d * 256 + c8 * 16, d)) =
        *(const short8*)(ST + ((size_t)b * D + d) * T + i * 128 + c8 * 8);
  }
#pragma unroll
  for (int it = 0; it < 4; ++it) {
    int s = tid + it * 512;
    int d = s >> 4, c8 = s & 15;
    *(short8*)((char*)Ct + swz(d * 256 + c8 * 16, d)) = *(const short8*)(C0 + coff + d * 128 + c8 * 8);
  }
  __syncthreads();

  f32x4 accO[8];
#pragma unroll
  for (int df = 0; df < 8; ++df) accO[df] = (f32x4)0.0f;
#pragma unroll
  for (int ks = 0; ks < 4; ++ks)
#pragma unroll
    for (int df = 0; df < 8; ++df) {
      int d = df * 16 + lq;
      bf16x8 bf = *(const bf16x8*)((const char*)Ct + swz(d * 256 + ks * 64 + lg * 16, d));
      accO[df] = mfma(aq[ks], bf, accO[df]);
    }
  f32x4 accP[8];
#pragma unroll
  for (int cf = 0; cf < 8; ++cf) accP[cf] = (f32x4)0.0f;
#pragma unroll
  for (int ks = 0; ks < 8; ++ks)
#pragma unroll
    for (int cf = 0; cf < 8; ++cf) {
      int tt = cf * 16 + lq;
      bf16x8 bf = *(const bf16x8*)((const char*)Hi + swz(tt * 512 + ks * 64 + lg * 16, tt));
      accP[cf] = mfma(aq[ks], bf, accP[cf]);
    }
  __syncthreads();

#pragma unroll
  for (int it = 0; it < 4; ++it) {
    int s = tid + it * 512;
    int d = s >> 4, c8 = s & 15;
    *(short8*)((char*)Ct + swz(d * 256 + c8 * 16, d)) = ct1r[it];
  }
  char* Pw = (char*)Hi + wid * 4096;
#pragma unroll
  for (int cf = 0; cf < 8; ++cf)
#pragma unroll
    for (int rr = 0; rr < 4; ++rr) {
      int ql = lg * 4 + rr;
      int tl = cf * 16 + lq;
      float v = accP[cf][rr];
      if (tl >= wid * 16 + ql) v = 0.0f;
      *(u16*)(Pw + swz(ql * 256 + tl * 2, ql)) = f2bf(v);
    }
  __syncthreads();

#pragma unroll
  for (int ks = 0; ks < 4; ++ks)
#pragma unroll
    for (int df = 0; df < 8; ++df) {
      int d = df * 16 + lq;
      bf16x8 bf = *(const bf16x8*)((const char*)Ct + swz(d * 256 + ks * 64 + lg * 16, d));
      accO[df] = mfma(aq[4 + ks], bf, accO[df]);
    }
#pragma unroll
  for (int ks = 0; ks < 4; ++ks) {
    bf16x8 a = *(const bf16x8*)(Pw + swz(lq * 256 + ks * 64 + lg * 16, lq));
#pragma unroll
    for (int df = 0; df < 8; ++df) {
      int d = df * 16 + lq;
      bf16x8 bf = *(const bf16x8*)((const char*)Sl + swz(d * 256 + ks * 64 + lg * 16, d));
      accO[df] = mfma(a, bf, accO[df]);
    }
  }

#pragma unroll
  for (int rr = 0; rr < 4; ++rr) {
    float ssum = 0.0f;
#pragma unroll
    for (int df = 0; df < 8; ++df) ssum += accO[df][rr];
#pragma unroll
    for (int off = 1; off < 16; off <<= 1) ssum += __shfl_xor(ssum, off);
    float inv = 1.0f / ssum;
    size_t row = hrow0 + wid * 16 + lg * 4 + rr;
#pragma unroll
    for (int df = 0; df < 8; ++df)
      out[row * D + df * 16 + lq] = accO[df][rr] * inv;
  }
}

// ---------------------------------------------------------------------------
extern "C" void kernel_launch(void* const* d_in, const int* in_sizes, int n_in,
                              void* d_out, int out_size, void* d_ws, size_t ws_size,
                              hipStream_t stream) {
  const float* batch = (const float*)d_in[0];
  const float* w0 = (const float*)d_in[1];
  const float* b0 = (const float*)d_in[2];
  const float* w1 = (const float*)d_in[3];
  const float* b1 = (const float*)d_in[4];
  const float* w2 = (const float*)d_in[5];
  const float* b2 = (const float*)d_in[6];
  const float* wo = (const float*)d_in[7];
  const float* bo = (const float*)d_in[8];

  const size_t SZ_S = 16777216;     // 16MB
  const size_t SZ_BUF = 33554432;   // 32MB
  const size_t ST_OFF = 88080384;   // 84MB — ST's own region (no clobber)
  const size_t NEED = ST_OFF + SZ_S;  // 100MB (harness ws = 256MB per poison fills)
  if (ws_size < NEED) return;

  char* ws = (char*)d_ws;
  // Layout:
  //  [0,16M):   G0/C0 (written by gchunk, after conv chain)
  //  [16M,48M): bufA (conv0/conv2 out; dead after conv_last) -> upper 16M = G1/C1
  //  [48M,80M): bufB = H (live to end)
  //  [80M,80.75M): weights
  //  [84M,100M): ST (written by prep, read by gchunk/attn — never clobbered)
  u16* bufA = (u16*)(ws + SZ_S);
  u16* bufB = (u16*)(ws + SZ_S + SZ_BUF);
  u16* Wt0 = (u16*)(ws + SZ_S + 2 * SZ_BUF);
  u16* Wt1 = Wt0 + 2 * 256 * 128;
  u16* Wt2 = Wt1 + 2 * 256 * 256;
  u16* Wt3 = Wt2 + 2 * 256 * 256;
  u16* ST = (u16*)(ws + ST_OFF);
  u16* G0 = (u16*)ws;
  u16* G1 = (u16*)(ws + 2 * SZ_S);
  float* probs = (float*)d_out;
  float* wfin = probs + (size_t)32 * 2048 * 128;

  prep<<<2560, 256, 0, stream>>>(batch, w0, w1, w2, wo, Wt0, Wt1, Wt2, Wt3, ST);

  conv_first<<<512, 512, 0, stream>>>(batch, Wt0, b0, bufA);
  conv_mid<2><<<512, 512, 0, stream>>>(bufA, Wt1, b1, bufB);
  conv_mid<4><<<512, 512, 0, stream>>>(bufB, Wt2, b2, bufA);
  conv_last<<<512, 512, 0, stream>>>(bufA, Wt3, bo, bufB);

  gchunk<<<dim3(32, 2, 16), 512, 0, stream>>>(bufB, ST, G0, G1);
  prefix_wfin<<<dim3(32, 2, 8), 256, 0, stream>>>(G0, G1, wfin);
  attn_chunk<<<dim3(32, 16), 512, 0, stream>>>(bufB, ST, G0, G1, probs);
}

// Round 16
// 172.711 us; speedup vs baseline: 1.1858x; 1.1044x over previous
//
#include <hip/hip_runtime.h>

using u16 = unsigned short;
using u32 = unsigned int;
using short8 = __attribute__((ext_vector_type(8))) short;
using short4v = __attribute__((ext_vector_type(4))) short;
using bf16x8 = __attribute__((ext_vector_type(8))) __bf16;
using f32x4 = __attribute__((ext_vector_type(4))) float;

#define ALPHA_INV (1.0f / (128.0f * 100.0f))

__device__ __forceinline__ u32 swz(u32 off, u32 row) { return off ^ ((row & 7u) << 4); }

__device__ __forceinline__ u16 f2bf(float x) {
  u32 u = __float_as_uint(x);
  u32 r = u + 0x7fffu + ((u >> 16) & 1u);
  return (u16)(r >> 16);
}

__device__ __forceinline__ float bf2f(u16 x) {
  u32 u = ((u32)x) << 16;
  return __uint_as_float(u);
}

__device__ __forceinline__ f32x4 mfma(bf16x8 a, bf16x8 b, f32x4 c) {
  return __builtin_amdgcn_mfma_f32_16x16x32_bf16(a, b, c, 0, 0, 0);
}

// async 16B global->LDS; LDS dest is wave-uniform base + lane*16
__device__ __forceinline__ void gl16(const void* g, void* l) {
  __builtin_amdgcn_global_load_lds(
      (const __attribute__((address_space(1))) unsigned int*)g,
      (__attribute__((address_space(3))) unsigned int*)l, 16, 0, 0);
}

// ---------------------------------------------------------------------------
// prep: weights transpose+bf16+pre-swizzle + batch fp32 -> ST (own region).
// ---------------------------------------------------------------------------
__global__ __launch_bounds__(256) void prep(
    const float* __restrict__ batch,
    const float* __restrict__ w0, const float* __restrict__ w1,
    const float* __restrict__ w2, const float* __restrict__ wo,
    u16* __restrict__ o0, u16* __restrict__ o1,
    u16* __restrict__ o2, u16* __restrict__ o3,
    u16* __restrict__ ST) {
  __shared__ u16 L[64 * 129];
  int blk = blockIdx.x;
  if (blk < 1536) {
    const float* w; u16* o; int cin;
    if (blk < 256)       { w = w0; o = o0; cin = 128; }
    else if (blk < 768)  { w = w1; o = o1; cin = 256; blk -= 256; }
    else if (blk < 1280) { w = w2; o = o2; cin = 256; blk -= 768; }
    else                 { w = wo; o = o3; cin = 256; blk -= 1280; }
    int idx = blk * 256 + threadIdx.x;
    int row = idx >> 8, n = idx & 255;
    int tap = row / cin, c = row - tap * cin;
    int kc = c >> 6, ci = c & 63;
    u32 sb = (u32)(ci * 2) ^ ((u32)(n & 7) << 4);
    o[((size_t)tap * 256 + n) * cin + kc * 64 + (sb >> 1)] = f2bf(w[idx]);
    return;
  }
  blk -= 1536;
  const int tid = threadIdx.x;
  const int t0 = (blk & 31) * 64;
  const int b = blk >> 5;
  const float* src = batch + ((size_t)b * 2048 + t0) * 128;
#pragma unroll
  for (int it = 0; it < 4; ++it) {
    int s = tid + it * 256;
    int t = s >> 4, c8 = s & 15;
    float4 v0 = *(const float4*)(src + t * 128 + c8 * 8);
    float4 v1 = *(const float4*)(src + t * 128 + c8 * 8 + 4);
    u16* p = &L[t * 129 + c8 * 8];
    p[0] = f2bf(v0.x); p[1] = f2bf(v0.y); p[2] = f2bf(v0.z); p[3] = f2bf(v0.w);
    p[4] = f2bf(v1.x); p[5] = f2bf(v1.y); p[6] = f2bf(v1.z); p[7] = f2bf(v1.w);
  }
  __syncthreads();
  u16* dst = ST + (size_t)b * 128 * 2048 + t0;
#pragma unroll
  for (int it = 0; it < 4; ++it) {
    int s = tid + it * 256;
    int oct = s & 7, d = s >> 3;
    short8 v;
#pragma unroll
    for (int j = 0; j < 8; ++j) v[j] = (short)L[(oct * 8 + j) * 129 + d];
    *(short8*)(dst + (size_t)d * 2048 + oct * 8) = v;
  }
}

// ---------------------------------------------------------------------------
// conv_first: CIN=128, 2 taps, dil=1, ReLU. Input = fp32 batch. (R13-proven)
// ---------------------------------------------------------------------------
__global__ __launch_bounds__(512) void conv_first(
    const float* __restrict__ in, const u16* __restrict__ wt,
    const float* __restrict__ bias, u16* __restrict__ out) {
  constexpr int CIN = 128, BN = 256;
  __shared__ alignas(16) u16 Al[128 * 64];
  __shared__ alignas(16) u16 Bl[256 * 64];

  const int tid = threadIdx.x;
  const int wid = tid >> 6, lane = tid & 63;
  const int wr = wid >> 2, wc = wid & 3;
  const int lg = lane >> 4, lq = lane & 15;
  const int row0 = blockIdx.x * 128;
  const int tloc0 = row0 & 2047;

  f32x4 acc[4][4];
#pragma unroll
  for (int i = 0; i < 4; ++i)
#pragma unroll
    for (int j = 0; j < 4; ++j) acc[i][j] = (f32x4)0.0f;

#pragma unroll
  for (int tap = 0; tap < 2; ++tap) {
    const int shift = 1 - tap;
#pragma unroll
    for (int kc = 0; kc < 2; ++kc) {
#pragma unroll
      for (int it = 0; it < 2; ++it) {
        int gi = tid + it * 512;
        int r = gi >> 3, cg = gi & 7;
        short8 v = (short8)0;
        if (!(tloc0 == 0 && r < shift)) {
          const float* src = in + (size_t)(row0 + r - shift) * CIN + kc * 64 + cg * 8;
          float4 a = *(const float4*)src;
          float4 b2 = *(const float4*)(src + 4);
          v[0] = (short)f2bf(a.x);  v[1] = (short)f2bf(a.y);
          v[2] = (short)f2bf(a.z);  v[3] = (short)f2bf(a.w);
          v[4] = (short)f2bf(b2.x); v[5] = (short)f2bf(b2.y);
          v[6] = (short)f2bf(b2.z); v[7] = (short)f2bf(b2.w);
        }
        *(short8*)((char*)Al + swz(r * 128 + cg * 16, (u32)(r - shift + 8))) = v;
      }
      {
        const u16* wtb = wt + ((size_t)(tap * 256)) * CIN + kc * 64;
#pragma unroll
        for (int it = 0; it < 4; ++it) {
          int gi = tid + it * 512;
          int n = gi >> 3, cg = gi & 7;
          gl16(wtb + (size_t)n * CIN + cg * 8, (char*)Bl + it * 8192 + wid * 1024);
        }
      }
      __syncthreads();
#pragma unroll
      for (int ks = 0; ks < 2; ++ks) {
        bf16x8 af[4], bfr[4];
#pragma unroll
        for (int mi = 0; mi < 4; ++mi) {
          int r = wr * 64 + mi * 16 + lq;
          af[mi] = *(const bf16x8*)((const char*)Al +
                                    swz(r * 128 + ks * 64 + lg * 16, (u32)(r - shift + 8)));
        }
#pragma unroll
        for (int ni = 0; ni < 4; ++ni) {
          int n = wc * 64 + ni * 16 + lq;
          bfr[ni] = *(const bf16x8*)((const char*)Bl + swz(n * 128 + ks * 64 + lg * 16, n));
        }
#pragma unroll
        for (int mi = 0; mi < 4; ++mi)
#pragma unroll
          for (int ni = 0; ni < 4; ++ni)
            acc[mi][ni] = mfma(af[mi], bfr[ni], acc[mi][ni]);
      }
      __syncthreads();
    }
  }

  float bcol[4];
#pragma unroll
  for (int ni = 0; ni < 4; ++ni) bcol[ni] = bias[wc * 64 + ni * 16 + lq];
#pragma unroll
  for (int mi = 0; mi < 4; ++mi)
#pragma unroll
    for (int ni = 0; ni < 4; ++ni)
#pragma unroll
      for (int rr = 0; rr < 4; ++rr) {
        float v = fmaxf(acc[mi][ni][rr] + bcol[ni], 0.0f);
        int row = row0 + wr * 64 + mi * 16 + lg * 4 + rr;
        int col = wc * 64 + ni * 16 + lq;
        int ci = col & 63;
        u32 sb = (u32)(ci * 2) ^ ((u32)(row & 7) << 4);
        out[(size_t)row * BN + wc * 64 + (sb >> 1)] = f2bf(v);
      }
}

// ---------------------------------------------------------------------------
// conv_mid<DIL>, 2-PHASE: double-buffered LDS; per (kc,tap) iteration:
// issue next-tile gl16s -> counted vmcnt(6/7) -> ONE raw barrier -> MFMA.
// Loads stay in flight across barriers (T3+T4). A restaged per tap (uniform).
// ---------------------------------------------------------------------------
template <int DIL>
__global__ __launch_bounds__(512) void conv_mid(
    const u16* __restrict__ in, const u16* __restrict__ wt,
    const float* __restrict__ bias, u16* __restrict__ out) {
  constexpr int CIN = 256, BN = 256;
  __shared__ alignas(16) u16 Al[2][136 * 64];
  __shared__ alignas(16) u16 Bl[2][256 * 64];

  const int tid = threadIdx.x;
  const int wid = tid >> 6, lane = tid & 63;
  const int wr = wid >> 2, wc = wid & 3;
  const int lg = lane >> 4, lq = lane & 15;
  const int row0 = blockIdx.x * 128;
  const int tloc0 = row0 & 2047;

  f32x4 acc[4][4];
#pragma unroll
  for (int i = 0; i < 4; ++i)
#pragma unroll
    for (int j = 0; j < 4; ++j) acc[i][j] = (f32x4)0.0f;

  // STAGE(buf, kc, tap): A (2 + wid0-tail) + B (4) gl16s per thread
#define STAGE_MID(BUF, KC, TAP)                                                          \
  {                                                                                      \
    _Pragma("unroll") for (int p = 0; p < 2; ++p) {                                      \
      int gi = tid + p * 512;                                                            \
      gl16(in + (size_t)(row0 - DIL + (gi >> 3)) * CIN + (KC)*64 + (gi & 7) * 8,         \
           (char*)Al[BUF] + p * 8192 + wid * 1024);                                      \
    }                                                                                    \
    if (wid == 0)                                                                        \
      gl16(in + (size_t)(row0 - DIL + 128 + (lane >> 3)) * CIN + (KC)*64 + (lane & 7) * 8,\
           (char*)Al[BUF] + 16384);                                                      \
    const u16* wtb = wt + (size_t)(TAP)*256 * CIN + (KC)*64;                             \
    _Pragma("unroll") for (int p = 0; p < 4; ++p) {                                      \
      int gi = tid + p * 512;                                                            \
      gl16(wtb + (size_t)(gi >> 3) * CIN + (gi & 7) * 8,                                 \
           (char*)Bl[BUF] + p * 8192 + wid * 1024);                                      \
    }                                                                                    \
  }

  STAGE_MID(0, 0, 0);  // prologue

#pragma unroll
  for (int it8 = 0; it8 < 8; ++it8) {
    const int buf = it8 & 1;
    const int tap = it8 & 1;        // iteration = (kc, tap): tap fast
    const int kc = it8 >> 1;
    // issue next tile
    if (it8 < 7) {
      const int nkc = (it8 + 1) >> 1, ntap = (it8 + 1) & 1, nbuf = (it8 + 1) & 1;
      STAGE_MID(nbuf, nkc, ntap);
      if (wid == 0)
        asm volatile("s_waitcnt vmcnt(7)" ::: "memory");
      else
        asm volatile("s_waitcnt vmcnt(6)" ::: "memory");
    } else {
      asm volatile("s_waitcnt vmcnt(0)" ::: "memory");
    }
    __builtin_amdgcn_s_barrier();
    if (tap == 0 && tloc0 == 0) {  // zero garbage rows < DIL (block-uniform)
      if (tid < DIL * 8) *(short8*)((char*)Al[buf] + tid * 16) = (short8)0;
      asm volatile("s_waitcnt lgkmcnt(0)" ::: "memory");
      __builtin_amdgcn_s_barrier();
    }
#pragma unroll
    for (int ks = 0; ks < 2; ++ks) {
      bf16x8 af[4], bfr[4];
#pragma unroll
      for (int mi = 0; mi < 4; ++mi) {
        int r = wr * 64 + mi * 16 + lq;
        if (tap == 0)
          af[mi] = *(const bf16x8*)((const char*)Al[buf] +
                                    swz(r * 128 + ks * 64 + lg * 16, (u32)(r - DIL + 8)));
        else
          af[mi] = *(const bf16x8*)((const char*)Al[buf] +
                                    swz((r + DIL) * 128 + ks * 64 + lg * 16, (u32)(r + 8)));
      }
#pragma unroll
      for (int ni = 0; ni < 4; ++ni) {
        int n = wc * 64 + ni * 16 + lq;
        bfr[ni] = *(const bf16x8*)((const char*)Bl[buf] + swz(n * 128 + ks * 64 + lg * 16, n));
      }
#pragma unroll
      for (int mi = 0; mi < 4; ++mi)
#pragma unroll
        for (int ni = 0; ni < 4; ++ni)
          acc[mi][ni] = mfma(af[mi], bfr[ni], acc[mi][ni]);
    }
  }
#undef STAGE_MID

  float bcol[4];
#pragma unroll
  for (int ni = 0; ni < 4; ++ni) bcol[ni] = bias[wc * 64 + ni * 16 + lq];
#pragma unroll
  for (int mi = 0; mi < 4; ++mi)
#pragma unroll
    for (int ni = 0; ni < 4; ++ni)
#pragma unroll
      for (int rr = 0; rr < 4; ++rr) {
        float v = fmaxf(acc[mi][ni][rr] + bcol[ni], 0.0f);
        int row = row0 + wr * 64 + mi * 16 + lg * 4 + rr;
        int col = wc * 64 + ni * 16 + lq;
        int ci = col & 63;
        u32 sb = (u32)(ci * 2) ^ ((u32)(row & 7) << 4);
        out[(size_t)row * BN + wc * 64 + (sb >> 1)] = f2bf(v);
      }
}

// ---------------------------------------------------------------------------
// conv_last, 2-PHASE: same discipline, uniform 6 loads/thread, 4 iterations.
// Fused softmax epilogue unchanged.
// ---------------------------------------------------------------------------
__global__ __launch_bounds__(512) void conv_last(
    const u16* __restrict__ in, const u16* __restrict__ wt,
    const float* __restrict__ bias, u16* __restrict__ out) {
  constexpr int CIN = 256, BN = 256;
  __shared__ alignas(16) u16 Al[2][128 * 64];
  __shared__ alignas(16) u16 Bl[2][256 * 64];
  __shared__ float redA[4][128];
  __shared__ float redB[4][128];

  const int tid = threadIdx.x;
  const int wid = tid >> 6, lane = tid & 63;
  const int wr = wid >> 2, wc = wid & 3;
  const int lg = lane >> 4, lq = lane & 15;
  const int row0 = blockIdx.x * 128;

  f32x4 acc[4][4];
#pragma unroll
  for (int i = 0; i < 4; ++i)
#pragma unroll
    for (int j = 0; j < 4; ++j) acc[i][j] = (f32x4)0.0f;

#define STAGE_LAST(BUF, KC)                                                              \
  {                                                                                      \
    _Pragma("unroll") for (int p = 0; p < 2; ++p) {                                      \
      int gi = tid + p * 512;                                                            \
      gl16(in + (size_t)(row0 + (gi >> 3)) * CIN + (KC)*64 + (gi & 7) * 8,               \
           (char*)Al[BUF] + p * 8192 + wid * 1024);                                      \
    }                                                                                    \
    const u16* wtb = wt + (KC)*64;                                                       \
    _Pragma("unroll") for (int p = 0; p < 4; ++p) {                                      \
      int gi = tid + p * 512;                                                            \
      gl16(wtb + (size_t)(gi >> 3) * CIN + (gi & 7) * 8,                                 \
           (char*)Bl[BUF] + p * 8192 + wid * 1024);                                      \
    }                                                                                    \
  }

  STAGE_LAST(0, 0);

#pragma unroll
  for (int it4 = 0; it4 < 4; ++it4) {
    const int buf = it4 & 1;
    if (it4 < 3) {
      STAGE_LAST((it4 + 1) & 1, it4 + 1);
      asm volatile("s_waitcnt vmcnt(6)" ::: "memory");
    } else {
      asm volatile("s_waitcnt vmcnt(0)" ::: "memory");
    }
    __builtin_amdgcn_s_barrier();
#pragma unroll
    for (int ks = 0; ks < 2; ++ks) {
      bf16x8 af[4], bfr[4];
#pragma unroll
      for (int mi = 0; mi < 4; ++mi) {
        int r = wr * 64 + mi * 16 + lq;
        af[mi] = *(const bf16x8*)((const char*)Al[buf] +
                                  swz(r * 128 + ks * 64 + lg * 16, (u32)(r + 8)));
      }
#pragma unroll
      for (int ni = 0; ni < 4; ++ni) {
        int n = wc * 64 + ni * 16 + lq;
        bfr[ni] = *(const bf16x8*)((const char*)Bl[buf] + swz(n * 128 + ks * 64 + lg * 16, n));
      }
#pragma unroll
      for (int mi = 0; mi < 4; ++mi)
#pragma unroll
        for (int ni = 0; ni < 4; ++ni)
          acc[mi][ni] = mfma(af[mi], bfr[ni], acc[mi][ni]);
    }
  }
#undef STAGE_LAST
  __syncthreads();  // redA/redB reuse below needs full sync semantics

  float bcol[4];
#pragma unroll
  for (int ni = 0; ni < 4; ++ni) bcol[ni] = bias[wc * 64 + ni * 16 + lq];
#pragma unroll
  for (int mi = 0; mi < 4; ++mi)
#pragma unroll
    for (int ni = 0; ni < 4; ++ni)
#pragma unroll
      for (int rr = 0; rr < 4; ++rr) acc[mi][ni][rr] += bcol[ni];

  float tmx[4][4];
#pragma unroll
  for (int mi = 0; mi < 4; ++mi)
#pragma unroll
    for (int rr = 0; rr < 4; ++rr) {
      float v = fmaxf(fmaxf(acc[mi][0][rr], acc[mi][1][rr]),
                      fmaxf(acc[mi][2][rr], acc[mi][3][rr]));
#pragma unroll
      for (int off = 1; off < 16; off <<= 1) v = fmaxf(v, __shfl_xor(v, off));
      if (lq == 0) redA[wc][wr * 64 + mi * 16 + lg * 4 + rr] = v;
    }
  __syncthreads();
#pragma unroll
  for (int mi = 0; mi < 4; ++mi)
#pragma unroll
    for (int rr = 0; rr < 4; ++rr) {
      int rb = wr * 64 + mi * 16 + lg * 4 + rr;
      tmx[mi][rr] = fmaxf(fmaxf(redA[0][rb], redA[1][rb]),
                          fmaxf(redA[2][rb], redA[3][rb]));
    }
#pragma unroll
  for (int mi = 0; mi < 4; ++mi)
#pragma unroll
    for (int rr = 0; rr < 4; ++rr) {
      float s = 0.0f;
#pragma unroll
      for (int ni = 0; ni < 4; ++ni) {
        float p = __expf(acc[mi][ni][rr] - tmx[mi][rr]);
        acc[mi][ni][rr] = p;
        s += p;
      }
#pragma unroll
      for (int off = 1; off < 16; off <<= 1) s += __shfl_xor(s, off);
      if (lq == 0) redB[wc][wr * 64 + mi * 16 + lg * 4 + rr] = s;
    }
  __syncthreads();
#pragma unroll
  for (int mi = 0; mi < 4; ++mi)
#pragma unroll
    for (int rr = 0; rr < 4; ++rr) {
      int rb = wr * 64 + mi * 16 + lg * 4 + rr;
      float inv = 1.0f / (redB[0][rb] + redB[1][rb] + redB[2][rb] + redB[3][rb]);
      int row = row0 + rb;
#pragma unroll
      for (int ni = 0; ni < 4; ++ni) {
        int col = wc * 64 + ni * 16 + lq;
        out[(size_t)row * BN + col] = f2bf(acc[mi][ni][rr] * inv);
      }
    }
}

// ---------------------------------------------------------------------------
// gchunk (unchanged)
// ---------------------------------------------------------------------------
__global__ __launch_bounds__(512) void gchunk(
    const u16* __restrict__ H, const u16* __restrict__ ST,
    u16* __restrict__ G0, u16* __restrict__ G1) {
  constexpr int M = 256, T = 2048;
  __shared__ alignas(16) u16 Hl[128 * 128];
  __shared__ alignas(16) u16 Sl[128 * 128];
  const int tid = threadIdx.x;
  const int wid = tid >> 6, lane = tid & 63;
  const int dg = wid >> 2, mg = wid & 3;
  const int lg = lane >> 4, lq = lane & 15;
  const int b = blockIdx.x, mh = blockIdx.y, j = blockIdx.z;
  u16* G = (mh == 0 ? G0 : G1);

#pragma unroll
  for (int it = 0; it < 4; ++it) {
    int s = tid + it * 512;
    int t = s >> 4, c8 = s & 15;
    short8 v = *(const short8*)(H + ((size_t)b * T + j * 128 + t) * M + mh * 128 + c8 * 8);
#pragma unroll
    for (int jj = 0; jj < 8; ++jj) {
      int ml = c8 * 8 + jj;
      *(u16*)((char*)Hl + swz(ml * 256 + t * 2, ml)) = (u16)v[jj];
    }
  }
#pragma unroll
  for (int it = 0; it < 4; ++it) {
    int s = tid + it * 512;
    int d = s >> 4, c8 = s & 15;
    *(short8*)((char*)Sl + swz(d * 256 + c8 * 16, d)) =
        *(const short8*)(ST + ((size_t)b * 128 + d) * T + j * 128 + c8 * 8);
  }
  __syncthreads();

  f32x4 acc[4][2];
#pragma unroll
  for (int di = 0; di < 4; ++di)
#pragma unroll
    for (int mi = 0; mi < 2; ++mi) acc[di][mi] = (f32x4)0.0f;

#pragma unroll
  for (int ks = 0; ks < 4; ++ks) {
    bf16x8 sfrag[4];
#pragma unroll
    for (int di = 0; di < 4; ++di) {
      int d = dg * 64 + di * 16 + lq;
      sfrag[di] = *(const bf16x8*)((const char*)Sl + swz(d * 256 + ks * 64 + lg * 16, d));
    }
#pragma unroll
    for (int mi = 0; mi < 2; ++mi) {
      int ml = mg * 32 + mi * 16 + lq;
      bf16x8 hfrag =
          *(const bf16x8*)((const char*)Hl + swz(ml * 256 + ks * 64 + lg * 16, ml));
#pragma unroll
      for (int di = 0; di < 4; ++di) acc[di][mi] = mfma(sfrag[di], hfrag, acc[di][mi]);
    }
  }

  u16* Gj = G + (((size_t)b * 16 + j) << 14);
#pragma unroll
  for (int di = 0; di < 4; ++di)
#pragma unroll
    for (int mi = 0; mi < 2; ++mi)
#pragma unroll
      for (int rr = 0; rr < 4; ++rr) {
        int d = dg * 64 + di * 16 + lg * 4 + rr;
        int ml = mg * 32 + mi * 16 + lq;
        Gj[d * 128 + ml] = f2bf(acc[di][mi][rr]);
      }
}

// ---------------------------------------------------------------------------
// prefix_wfin (unchanged)
// ---------------------------------------------------------------------------
__global__ __launch_bounds__(256) void prefix_wfin(
    u16* __restrict__ G0, u16* __restrict__ G1, float* __restrict__ wfin) {
  __shared__ float Wl[16][132];
  const int b = blockIdx.x, mh = blockIdx.y, ds = blockIdx.z;
  u16* G = mh ? G1 : G0;
  const int tid = threadIdx.x;
  const int mo = tid & 15, dg = tid >> 4;
  const int d = ds * 16 + dg;
  size_t base = (((size_t)b * 16) << 14) + d * 128 + mo * 8;
  float acc[8];
#pragma unroll
  for (int k = 0; k < 8; ++k) acc[k] = ALPHA_INV;
  for (int j = 0; j < 16; ++j) {
    u16* p = G + base + ((size_t)j << 14);
    short8 g = *(short8*)p;
    short8 c;
#pragma unroll
    for (int k = 0; k < 8; ++k) c[k] = (short)f2bf(acc[k]);
    *(short8*)p = c;
#pragma unroll
    for (int k = 0; k < 8; ++k) acc[k] += bf2f((u16)g[k]);
  }
#pragma unroll
  for (int k = 0; k < 8; ++k) Wl[dg][mo * 8 + k] = acc[k];
  __syncthreads();
  const int ml = tid >> 1, dq = tid & 1;
  const int dl0 = dq * 8;
  float* dst = wfin + ((size_t)b * 256 + mh * 128 + ml) * 128 + ds * 16 + dl0;
  float4 v0 = make_float4(Wl[dl0][ml], Wl[dl0 + 1][ml], Wl[dl0 + 2][ml], Wl[dl0 + 3][ml]);
  float4 v1 = make_float4(Wl[dl0 + 4][ml], Wl[dl0 + 5][ml], Wl[dl0 + 6][ml], Wl[dl0 + 7][ml]);
  *(float4*)dst = v0;
  *(float4*)(dst + 4) = v1;
}

// ---------------------------------------------------------------------------
// attn_chunk (R13-proven, 3 barriers, Hi from registers)
// ---------------------------------------------------------------------------
__global__ __launch_bounds__(512) void attn_chunk(
    const u16* __restrict__ H, const u16* __restrict__ ST,
    const u16* __restrict__ C0, const u16* __restrict__ C1,
    float* __restrict__ out) {
  constexpr int M = 256, D = 128, T = 2048;
  __shared__ alignas(16) u16 Hi[128 * 256];
  __shared__ alignas(16) u16 Sl[128 * 128];
  __shared__ alignas(16) u16 Ct[128 * 128];

  const int tid = threadIdx.x;
  const int wid = tid >> 6, lane = tid & 63;
  const int lg = lane >> 4, lq = lane & 15;
  const int b = blockIdx.x, i = blockIdx.y;
  const size_t hrow0 = (size_t)b * T + i * 128;
  const size_t coff = ((size_t)b * 16 + i) * (128 * 128);

  bf16x8 aq[8];
  {
    const u16* qrow = H + (hrow0 + wid * 16 + lq) * M;
#pragma unroll
    for (int ks = 0; ks < 8; ++ks) aq[ks] = *(const bf16x8*)(qrow + ks * 32 + lg * 8);
  }

  short8 ct1r[4];
#pragma unroll
  for (int it = 0; it < 4; ++it) {
    int s = tid + it * 512;
    int d = s >> 4, c8 = s & 15;
    ct1r[it] = *(const short8*)(C1 + coff + d * 128 + c8 * 8);
  }

  {
    int r = wid * 16 + lq;
#pragma unroll
    for (int ks = 0; ks < 8; ++ks)
      *(short8*)((char*)Hi + swz(r * 512 + ks * 64 + lg * 16, r)) =
          __builtin_bit_cast(short8, aq[ks]);
  }
#pragma unroll
  for (int it = 0; it < 4; ++it) {
    int s = tid + it * 512;
    int d = s >> 4, c8 = s & 15;
    *(short8*)((char*)Sl + swz(d * 256 + c8 * 16, d)) =
        *(const short8*)(ST + ((size_t)b * D + d) * T + i * 128 + c8 * 8);
  }
#pragma unroll
  for (int it = 0; it < 4; ++it) {
    int s = tid + it * 512;
    int d = s >> 4, c8 = s & 15;
    *(short8*)((char*)Ct + swz(d * 256 + c8 * 16, d)) = *(const short8*)(C0 + coff + d * 128 + c8 * 8);
  }
  __syncthreads();

  f32x4 accO[8];
#pragma unroll
  for (int df = 0; df < 8; ++df) accO[df] = (f32x4)0.0f;
#pragma unroll
  for (int ks = 0; ks < 4; ++ks)
#pragma unroll
    for (int df = 0; df < 8; ++df) {
      int d = df * 16 + lq;
      bf16x8 bf = *(const bf16x8*)((const char*)Ct + swz(d * 256 + ks * 64 + lg * 16, d));
      accO[df] = mfma(aq[ks], bf, accO[df]);
    }
  f32x4 accP[8];
#pragma unroll
  for (int cf = 0; cf < 8; ++cf) accP[cf] = (f32x4)0.0f;
#pragma unroll
  for (int ks = 0; ks < 8; ++ks)
#pragma unroll
    for (int cf = 0; cf < 8; ++cf) {
      int tt = cf * 16 + lq;
      bf16x8 bf = *(const bf16x8*)((const char*)Hi + swz(tt * 512 + ks * 64 + lg * 16, tt));
      accP[cf] = mfma(aq[ks], bf, accP[cf]);
    }
  __syncthreads();

#pragma unroll
  for (int it = 0; it < 4; ++it) {
    int s = tid + it * 512;
    int d = s >> 4, c8 = s & 15;
    *(short8*)((char*)Ct + swz(d * 256 + c8 * 16, d)) = ct1r[it];
  }
  char* Pw = (char*)Hi + wid * 4096;
#pragma unroll
  for (int cf = 0; cf < 8; ++cf)
#pragma unroll
    for (int rr = 0; rr < 4; ++rr) {
      int ql = lg * 4 + rr;
      int tl = cf * 16 + lq;
      float v = accP[cf][rr];
      if (tl >= wid * 16 + ql) v = 0.0f;
      *(u16*)(Pw + swz(ql * 256 + tl * 2, ql)) = f2bf(v);
    }
  __syncthreads();

#pragma unroll
  for (int ks = 0; ks < 4; ++ks)
#pragma unroll
    for (int df = 0; df < 8; ++df) {
      int d = df * 16 + lq;
      bf16x8 bf = *(const bf16x8*)((const char*)Ct + swz(d * 256 + ks * 64 + lg * 16, d));
      accO[df] = mfma(aq[4 + ks], bf, accO[df]);
    }
#pragma unroll
  for (int ks = 0; ks < 4; ++ks) {
    bf16x8 a = *(const bf16x8*)(Pw + swz(lq * 256 + ks * 64 + lg * 16, lq));
#pragma unroll
    for (int df = 0; df < 8; ++df) {
      int d = df * 16 + lq;
      bf16x8 bf = *(const bf16x8*)((const char*)Sl + swz(d * 256 + ks * 64 + lg * 16, d));
      accO[df] = mfma(a, bf, accO[df]);
    }
  }

#pragma unroll
  for (int rr = 0; rr < 4; ++rr) {
    float ssum = 0.0f;
#pragma unroll
    for (int df = 0; df < 8; ++df) ssum += accO[df][rr];
#pragma unroll
    for (int off = 1; off < 16; off <<= 1) ssum += __shfl_xor(ssum, off);
    float inv = 1.0f / ssum;
    size_t row = hrow0 + wid * 16 + lg * 4 + rr;
#pragma unroll
    for (int df = 0; df < 8; ++df)
      out[row * D + df * 16 + lq] = accO[df][rr] * inv;
  }
}

// ---------------------------------------------------------------------------
extern "C" void kernel_launch(void* const* d_in, const int* in_sizes, int n_in,
                              void* d_out, int out_size, void* d_ws, size_t ws_size,
                              hipStream_t stream) {
  const float* batch = (const float*)d_in[0];
  const float* w0 = (const float*)d_in[1];
  const float* b0 = (const float*)d_in[2];
  const float* w1 = (const float*)d_in[3];
  const float* b1 = (const float*)d_in[4];
  const float* w2 = (const float*)d_in[5];
  const float* b2 = (const float*)d_in[6];
  const float* wo = (const float*)d_in[7];
  const float* bo = (const float*)d_in[8];

  const size_t SZ_S = 16777216;     // 16MB
  const size_t SZ_BUF = 33554432;   // 32MB
  const size_t ST_OFF = 88080384;   // 84MB — ST's own region
  const size_t NEED = ST_OFF + SZ_S;
  if (ws_size < NEED) return;

  char* ws = (char*)d_ws;
  u16* bufA = (u16*)(ws + SZ_S);
  u16* bufB = (u16*)(ws + SZ_S + SZ_BUF);
  u16* Wt0 = (u16*)(ws + SZ_S + 2 * SZ_BUF);
  u16* Wt1 = Wt0 + 2 * 256 * 128;
  u16* Wt2 = Wt1 + 2 * 256 * 256;
  u16* Wt3 = Wt2 + 2 * 256 * 256;
  u16* ST = (u16*)(ws + ST_OFF);
  u16* G0 = (u16*)ws;
  u16* G1 = (u16*)(ws + 2 * SZ_S);
  float* probs = (float*)d_out;
  float* wfin = probs + (size_t)32 * 2048 * 128;

  prep<<<2560, 256, 0, stream>>>(batch, w0, w1, w2, wo, Wt0, Wt1, Wt2, Wt3, ST);

  conv_first<<<512, 512, 0, stream>>>(batch, Wt0, b0, bufA);
  conv_mid<2><<<512, 512, 0, stream>>>(bufA, Wt1, b1, bufB);
  conv_mid<4><<<512, 512, 0, stream>>>(bufB, Wt2, b2, bufA);
  conv_last<<<512, 512, 0, stream>>>(bufA, Wt3, bo, bufB);

  gchunk<<<dim3(32, 2, 16), 512, 0, stream>>>(bufB, ST, G0, G1);
  prefix_wfin<<<dim3(32, 2, 8), 256, 0, stream>>>(G0, G1, wfin);
  attn_chunk<<<dim3(32, 16), 512, 0, stream>>>(bufB, ST, G0, G1, probs);
}